// Round 2
// baseline (1670.168 us; speedup 1.0000x reference)
//
#include <hip/hip_runtime.h>

#define B_ 2
#define T_ 1024
#define H_ 8
#define D_ 64

typedef __attribute__((ext_vector_type(8))) short s8v;
typedef __attribute__((ext_vector_type(4))) short s4v;
typedef __attribute__((ext_vector_type(4))) float f4v;

__device__ __forceinline__ short f2bf(float f) {
  unsigned u = __float_as_uint(f);
  u += 0x7fffu + ((u >> 16) & 1u);
  return (short)(u >> 16);
}
__device__ __forceinline__ float bf2f(short s) {
  return __uint_as_float(((unsigned)(unsigned short)s) << 16);
}
__device__ __forceinline__ float sigm(float v) { return 1.0f / (1.0f + __expf(-v)); }

#define MFMA(a, b, c) __builtin_amdgcn_mfma_f32_16x16x32_bf16((a), (b), (c), 0, 0, 0)

// ---------------- GEMM: Co[M,N] = A[M,K] @ Bw[N,K]^T  (fp32 io, split-bf16) -
__global__ __launch_bounds__(256) void gemm_bt(const float* __restrict__ A,
    const float* __restrict__ Bw, float* __restrict__ Co,
    int M, int N, int K) {
  __shared__ short Ash[64][40], Asl[64][40];
  __shared__ short Bsh[64][40], Bsl[64][40];
  const int tid = threadIdx.x;
  const int lane = tid & 63;
  const int wv = tid >> 6;
  const int wr = (wv >> 1) * 32;
  const int wc = (wv & 1) * 32;
  const int m0 = blockIdx.x * 64;
  const int n0 = blockIdx.y * 64;
  const int ldr = tid >> 2;
  const int ldc = (tid & 3) * 8;
  const int l15 = lane & 15;
  const int kq = (lane >> 4) * 8;
  f4v acc[2][2];
#pragma unroll
  for (int i = 0; i < 2; ++i)
#pragma unroll
    for (int j = 0; j < 2; ++j)
#pragma unroll
      for (int r = 0; r < 4; ++r) acc[i][j][r] = 0.0f;
  const float* ap = A + (size_t)(m0 + ldr) * K + ldc;
  const float* bp = Bw + (size_t)(n0 + ldr) * K + ldc;
  for (int kt = 0; kt < K; kt += 32) {
    float4 av0 = *(const float4*)(ap + kt);
    float4 av1 = *(const float4*)(ap + kt + 4);
    float4 bv0 = *(const float4*)(bp + kt);
    float4 bv1 = *(const float4*)(bp + kt + 4);
    float af[8] = {av0.x, av0.y, av0.z, av0.w, av1.x, av1.y, av1.z, av1.w};
    float bf[8] = {bv0.x, bv0.y, bv0.z, bv0.w, bv1.x, bv1.y, bv1.z, bv1.w};
    s8v ah, al, bh, bl;
#pragma unroll
    for (int i = 0; i < 8; ++i) {
      short h = f2bf(af[i]); ah[i] = h; al[i] = f2bf(af[i] - bf2f(h));
      h = f2bf(bf[i]); bh[i] = h; bl[i] = f2bf(bf[i] - bf2f(h));
    }
    __syncthreads();
    *(s8v*)&Ash[ldr][ldc] = ah; *(s8v*)&Asl[ldr][ldc] = al;
    *(s8v*)&Bsh[ldr][ldc] = bh; *(s8v*)&Bsl[ldr][ldc] = bl;
    __syncthreads();
    s8v a0h = *(const s8v*)&Ash[wr + l15][kq];
    s8v a1h = *(const s8v*)&Ash[wr + 16 + l15][kq];
    s8v b0h = *(const s8v*)&Bsh[wc + l15][kq];
    s8v b1h = *(const s8v*)&Bsh[wc + 16 + l15][kq];
    s8v a0l = *(const s8v*)&Asl[wr + l15][kq];
    s8v a1l = *(const s8v*)&Asl[wr + 16 + l15][kq];
    s8v b0l = *(const s8v*)&Bsl[wc + l15][kq];
    s8v b1l = *(const s8v*)&Bsl[wc + 16 + l15][kq];
    acc[0][0] = MFMA(a0h, b0h, acc[0][0]);
    acc[0][1] = MFMA(a0h, b1h, acc[0][1]);
    acc[1][0] = MFMA(a1h, b0h, acc[1][0]);
    acc[1][1] = MFMA(a1h, b1h, acc[1][1]);
    acc[0][0] = MFMA(a0h, b0l, acc[0][0]);
    acc[0][1] = MFMA(a0h, b1l, acc[0][1]);
    acc[1][0] = MFMA(a1h, b0l, acc[1][0]);
    acc[1][1] = MFMA(a1h, b1l, acc[1][1]);
    acc[0][0] = MFMA(a0l, b0h, acc[0][0]);
    acc[0][1] = MFMA(a0l, b1h, acc[0][1]);
    acc[1][0] = MFMA(a1l, b0h, acc[1][0]);
    acc[1][1] = MFMA(a1l, b1h, acc[1][1]);
  }
#pragma unroll
  for (int m2 = 0; m2 < 2; ++m2)
#pragma unroll
    for (int n2 = 0; n2 < 2; ++n2)
#pragma unroll
      for (int r = 0; r < 4; ++r) {
        int row = m0 + wr + m2 * 16 + (lane >> 4) * 4 + r;
        int col = n0 + wc + n2 * 16 + l15;
        Co[(size_t)row * N + col] = acc[m2][n2][r];
      }
}

// ---------------- causal depthwise conv (K=4) + bias + phi scale ------------
__global__ __launch_bounds__(256) void conv_k(const float* __restrict__ in,
    const float* __restrict__ w, const float* __restrict__ bias,
    const float* __restrict__ pc, float* __restrict__ outp) {
  int idx = blockIdx.x * 256 + threadIdx.x;   // < B*T*512
  int d = idx & 511;
  int bt = idx >> 9;
  int t = bt & (T_ - 1);
  float acc = bias[d];
#pragma unroll
  for (int j = 0; j < 4; ++j) {
    int tt = t - 3 + j;
    if (tt >= 0) acc += w[d * 4 + j] * in[(size_t)(bt - 3 + j) * 512 + d];
  }
  float sc = pc ? pc[0] : 1.0f;
  outp[idx] = sc * acc;
}

// ---------------- gates: 5 x (B,T,H) sigmoid projections --------------------
__global__ __launch_bounds__(256) void gates_k(const float* __restrict__ x,
    const float* __restrict__ gaw, const float* __restrict__ gab,
    const float* __restrict__ gew, const float* __restrict__ geb,
    const float* __restrict__ gtw, const float* __restrict__ gtb,
    const float* __restrict__ ggw, const float* __restrict__ ggb,
    const float* __restrict__ rgw,
    float* __restrict__ alpha, float* __restrict__ eta,
    float* __restrict__ theta, float* __restrict__ gam, float* __restrict__ rg) {
  int wv = threadIdx.x >> 6, lane = threadIdx.x & 63;
  int bt = blockIdx.x * 4 + wv;   // < B*T
  float xr[8];
#pragma unroll
  for (int i = 0; i < 8; ++i) xr[i] = x[(size_t)bt * 512 + i * 64 + lane];
  for (int h = 0; h < 8; ++h) {
    float s0 = 0, s1 = 0, s2 = 0, s3 = 0, s4 = 0;
#pragma unroll
    for (int i = 0; i < 8; ++i) {
      float xv = xr[i];
      int o = h * 512 + i * 64 + lane;
      s0 += xv * gaw[o];
      s1 += xv * gew[o];
      s2 += xv * gtw[o];
      s3 += xv * ggw[o];
      s4 += xv * rgw[o];
    }
#pragma unroll
    for (int off = 32; off >= 1; off >>= 1) {
      s0 += __shfl_xor(s0, off);
      s1 += __shfl_xor(s1, off);
      s2 += __shfl_xor(s2, off);
      s3 += __shfl_xor(s3, off);
      s4 += __shfl_xor(s4, off);
    }
    if (lane == 0) {
      size_t o = (size_t)bt * 8 + h;
      alpha[o] = sigm(s0 + gab[h]);
      eta[o]   = 0.1f * sigm(s1 + geb[h]);
      theta[o] = sigm(s2 + gtb[h]);
      gam[o]   = sigm(s3 + ggb[h]);
      rg[o]    = sigm(s4);
    }
  }
}

// ---------------- init M/S carries ------------------------------------------
__global__ __launch_bounds__(256) void init_carry(const float* __restrict__ w1,
    float* __restrict__ Mc, float* __restrict__ Sc) {
  int idx = blockIdx.x * 256 + threadIdx.x;   // < 65536
  Mc[idx] = w1[idx & 32767];
  Sc[idx] = 0.0f;
}

// ---------------- per-chunk: err -> omega window -> S scan (all fp32) -------
__global__ __launch_bounds__(256) void chunk_a(
    const float* __restrict__ kb, const float* __restrict__ vb,
    const float* __restrict__ eta, const float* __restrict__ theta,
    const float* __restrict__ gam,
    const float* __restrict__ Mc, float* __restrict__ Sc,
    float* __restrict__ chS, int ci) {
  __shared__ float KT[64][65];   // KT[k][c]
  __shared__ float errl[4][68];  // err[vr][c]
  __shared__ float Ml[4][64];
  __shared__ float ge_[64], gt_[64], gg_[64];
  const int tid = threadIdx.x;
  const int bh = blockIdx.x >> 4;        // 0..15
  const int vs = blockIdx.x & 15;
  const int b = bh >> 3, h = bh & 7;
  const int v0 = vs * 4;
  const int t0 = ci * 64;
  const int lane = tid & 63, q4 = tid >> 6;
  for (int it = 0; it < 16; ++it) {
    int c = it * 4 + q4;
    KT[lane][c] = kb[((size_t)(b * T_ + t0 + c) * H_ + h) * 64 + lane];
  }
  if (tid < 64) {
    size_t gi = (size_t)(b * T_ + t0 + tid) * H_ + h;
    ge_[tid] = eta[gi]; gt_[tid] = theta[gi]; gg_[tid] = gam[gi];
  }
  Ml[q4][lane] = Mc[((size_t)bh * 64 + v0 + q4) * 64 + lane];
  __syncthreads();
  // phase 1: err[vr][c] = (K M^T)[c][v] - V[c][v]
  {
    int c = lane, vr = q4;
    float p = 0.0f;
#pragma unroll
    for (int k2 = 0; k2 < 64; ++k2) p += KT[k2][c] * Ml[vr][k2];
    float vv = vb[((size_t)(b * T_ + t0 + c) * H_ + h) * 64 + v0 + vr];
    errl[vr][c] = p - vv;
  }
  __syncthreads();
  // phase 2: per-(v,k) recurrence over 64 timesteps
  {
    const int kk = lane, vr = q4, v = v0 + vr;
    float S = Sc[((size_t)bh * 64 + v) * 64 + kk];
    float ring[8];
    float cum = 0.0f;
    const size_t eoff = (size_t)v * 64 + kk;
    for (int c8 = 0; c8 < 8; ++c8) {
#pragma unroll
      for (int j = 0; j < 8; ++j) {
        int c = c8 * 8 + j;
        float u = 0.03125f * errl[vr][c] * KT[kk][c];
        float gu = gg_[c] * u;
        cum += gu;
        if (c8 > 0) cum -= ring[j];
        ring[j] = gu;
        float mom = -ge_[c] * cum;
        S = gt_[c] * S + mom;
        chS[((size_t)((b << 6) + c) * 8 + h) * 4096 + eoff] = S;
      }
    }
    Sc[((size_t)bh * 64 + v) * 64 + kk] = S;
  }
}

// ---------------- split-precision 64x64 matmul helper -----------------------
__device__ __forceinline__ void zacc(f4v acc[2][2]) {
#pragma unroll
  for (int i = 0; i < 2; ++i)
#pragma unroll
    for (int j = 0; j < 2; ++j)
#pragma unroll
      for (int r = 0; r < 4; ++r) acc[i][j][r] = 0.0f;
}

__device__ __forceinline__ void mm64(const short (*Ah)[72], const short (*Al)[72],
    const short (*Bh)[72], const short (*Bl)[72],
    int wr, int wc, int l15, int kq, int sp, f4v acc[2][2]) {
#pragma unroll
  for (int kt = 0; kt < 64; kt += 32) {
    s8v ah0 = *(const s8v*)&Ah[wr + l15][kt + kq];
    s8v ah1 = *(const s8v*)&Ah[wr + 16 + l15][kt + kq];
    s8v bh0 = *(const s8v*)&Bh[wc + l15][kt + kq];
    s8v bh1 = *(const s8v*)&Bh[wc + 16 + l15][kt + kq];
    acc[0][0] = MFMA(ah0, bh0, acc[0][0]);
    acc[0][1] = MFMA(ah0, bh1, acc[0][1]);
    acc[1][0] = MFMA(ah1, bh0, acc[1][0]);
    acc[1][1] = MFMA(ah1, bh1, acc[1][1]);
    if (sp) {
      s8v al0 = *(const s8v*)&Al[wr + l15][kt + kq];
      s8v al1 = *(const s8v*)&Al[wr + 16 + l15][kt + kq];
      s8v bl0 = *(const s8v*)&Bl[wc + l15][kt + kq];
      s8v bl1 = *(const s8v*)&Bl[wc + 16 + l15][kt + kq];
      acc[0][0] = MFMA(ah0, bl0, acc[0][0]);
      acc[0][1] = MFMA(ah0, bl1, acc[0][1]);
      acc[1][0] = MFMA(ah1, bl0, acc[1][0]);
      acc[1][1] = MFMA(ah1, bl1, acc[1][1]);
      acc[0][0] = MFMA(al0, bh0, acc[0][0]);
      acc[0][1] = MFMA(al0, bh1, acc[0][1]);
      acc[1][0] = MFMA(al1, bh0, acc[1][0]);
      acc[1][1] = MFMA(al1, bh1, acc[1][1]);
    }
  }
}

// ---------------- polar express (5 NS quintic iters), split precision -------
// LDS: Xh/Xl double as A (A = X X^T is symmetric; X rows dead after phase 1).
__global__ __launch_bounds__(256) void polar_k(float* __restrict__ cs) {
  __shared__ short Xh[64][72], Xl[64][72];     // X rows, then A rows
  __shared__ short XTh[64][72], XTl[64][72];   // X^T rows (element access + phase2 B)
  __shared__ short PTh[64][72], PTl[64][72];   // P^T rows
  __shared__ float red[4];
  const int tid = threadIdx.x;
  const int lane = tid & 63;
  const int wv = tid >> 6;
  const int wr = (wv >> 1) * 32;
  const int wc = (wv & 1) * 32;
  const int l15 = lane & 15;
  const int q4 = lane >> 4;
  const int kq = q4 * 8;
  float* base = cs + (size_t)blockIdx.x * 4096;
  const int row = tid >> 2;
  const int col0 = (tid & 3) * 16;
  float fv[16];
  float ss = 0.0f;
#pragma unroll
  for (int i = 0; i < 4; ++i) {
    float4 t = *(const float4*)(base + row * 64 + col0 + i * 4);
    fv[i * 4 + 0] = t.x; fv[i * 4 + 1] = t.y; fv[i * 4 + 2] = t.z; fv[i * 4 + 3] = t.w;
  }
#pragma unroll
  for (int i = 0; i < 16; ++i) ss += fv[i] * fv[i];
#pragma unroll
  for (int off = 32; off >= 1; off >>= 1) ss += __shfl_xor(ss, off);
  if (lane == 0) red[wv] = ss;
  __syncthreads();
  float scale = 1.0f / (sqrtf(red[0] + red[1] + red[2] + red[3]) * 1.01f + 1e-7f);
#pragma unroll
  for (int i = 0; i < 16; ++i) {
    float xv = fv[i] * scale;
    short h = f2bf(xv);
    short l = f2bf(xv - bf2f(h));
    int c = col0 + i;
    Xh[row][c] = h; Xl[row][c] = l;
    XTh[c][row] = h; XTl[c][row] = l;
  }
  __syncthreads();

  for (int it = 0; it < 5; ++it) {
    const int sp = (it < 4);
    f4v acc[2][2];
    // ---- phase 1: A = X X^T ; store (symmetric) transposed into Xh/Xl ----
    zacc(acc);
    mm64(Xh, Xl, Xh, Xl, wr, wc, l15, kq, sp, acc);
    __syncthreads();                 // all X-row reads done before overwrite
#pragma unroll
    for (int m2 = 0; m2 < 2; ++m2)
#pragma unroll
      for (int n2 = 0; n2 < 2; ++n2) {
        s4v hv, lv;
#pragma unroll
        for (int r = 0; r < 4; ++r) {
          float a = acc[m2][n2][r];
          short h = f2bf(a); hv[r] = h; lv[r] = f2bf(a - bf2f(h));
        }
        int rr0 = wr + m2 * 16 + q4 * 4, cc = wc + n2 * 16 + l15;
        *(s4v*)&Xh[cc][rr0] = hv;
        *(s4v*)&Xl[cc][rr0] = lv;
      }
    __syncthreads();
    // ---- phase 2: P = A X ; store P^T ----
    zacc(acc);
    mm64(Xh, Xl, XTh, XTl, wr, wc, l15, kq, sp, acc);
#pragma unroll
    for (int m2 = 0; m2 < 2; ++m2)
#pragma unroll
      for (int n2 = 0; n2 < 2; ++n2) {
        s4v hv, lv;
#pragma unroll
        for (int r = 0; r < 4; ++r) {
          float p = acc[m2][n2][r];
          short h = f2bf(p); hv[r] = h; lv[r] = f2bf(p - bf2f(h));
        }
        int rr0 = wr + m2 * 16 + q4 * 4, cc = wc + n2 * 16 + l15;
        *(s4v*)&PTh[cc][rr0] = hv;
        *(s4v*)&PTl[cc][rr0] = lv;
      }
    __syncthreads();
    // ---- phase 3: Q = A P ; X_new = a X + b P + c Q ----
    zacc(acc);
    mm64(Xh, Xl, PTh, PTl, wr, wc, l15, kq, sp, acc);
    __syncthreads();                 // all A-row reads done before X overwrite
#pragma unroll
    for (int m2 = 0; m2 < 2; ++m2)
#pragma unroll
      for (int n2 = 0; n2 < 2; ++n2) {
        int rr0 = wr + m2 * 16 + q4 * 4, cc = wc + n2 * 16 + l15;
        s4v xh4 = *(const s4v*)&XTh[cc][rr0];
        s4v xl4 = *(const s4v*)&XTl[cc][rr0];
        s4v ph4 = *(const s4v*)&PTh[cc][rr0];
        s4v pl4 = *(const s4v*)&PTl[cc][rr0];
        s4v nh, nl;
#pragma unroll
        for (int r = 0; r < 4; ++r) {
          float xv = bf2f(xh4[r]) + bf2f(xl4[r]);
          float pv = bf2f(ph4[r]) + bf2f(pl4[r]);
          float xn = 3.4445f * xv - 4.7750f * pv + 2.0315f * acc[m2][n2][r];
          short h = f2bf(xn); nh[r] = h; nl[r] = f2bf(xn - bf2f(h));
        }
        *(s4v*)&XTh[cc][rr0] = nh;
        *(s4v*)&XTl[cc][rr0] = nl;
#pragma unroll
        for (int r = 0; r < 4; ++r) {
          Xh[rr0 + r][cc] = nh[r];
          Xl[rr0 + r][cc] = nl[r];
        }
      }
    __syncthreads();
  }
  // write back fp32 (in place)
#pragma unroll
  for (int i = 0; i < 4; ++i) {
    float4 t;
    t.x = bf2f(Xh[row][col0 + i * 4 + 0]) + bf2f(Xl[row][col0 + i * 4 + 0]);
    t.y = bf2f(Xh[row][col0 + i * 4 + 1]) + bf2f(Xl[row][col0 + i * 4 + 1]);
    t.z = bf2f(Xh[row][col0 + i * 4 + 2]) + bf2f(Xl[row][col0 + i * 4 + 2]);
    t.w = bf2f(Xh[row][col0 + i * 4 + 3]) + bf2f(Xl[row][col0 + i * 4 + 3]);
    *(float4*)(base + row * 64 + col0 + i * 4) = t;
  }
}

// ---------------- per-chunk: M scan + y = M_t q_t ---------------------------
__global__ __launch_bounds__(256) void chunk_c(
    const float* __restrict__ orth, const float* __restrict__ alpha,
    const float* __restrict__ qb, float* __restrict__ Mc,
    float* __restrict__ yb, int ci) {
  const int lane = threadIdx.x & 63;
  const int gw = blockIdx.x * 4 + (threadIdx.x >> 6);  // < 1024
  const int v = gw & 63, h = (gw >> 6) & 7, b = gw >> 9;
  const int bh = b * 8 + h;
  const int t0 = ci * 64;
  float M = Mc[((size_t)bh * 64 + v) * 64 + lane];
  for (int c = 0; c < 64; ++c) {
    size_t mi = (size_t)((b << 6) + c) * 8 + h;
    float o = orth[mi * 4096 + (size_t)v * 64 + lane];
    float al = alpha[(size_t)(b * T_ + t0 + c) * 8 + h];
    M = al * M + o;
    float qv = qb[((size_t)(b * T_ + t0 + c) * 8 + h) * 64 + lane];
    float p = M * qv;
#pragma unroll
    for (int off = 32; off >= 1; off >>= 1) p += __shfl_xor(p, off);
    if (lane == 0) yb[((size_t)(b * T_ + t0 + c) * 8 + h) * 64 + v] = p;
  }
  Mc[((size_t)bh * 64 + v) * 64 + lane] = M;
}

// ---------------- RMS-norm * (1+ln_gamma) * rg ------------------------------
__global__ __launch_bounds__(256) void norm_k(const float* __restrict__ yb,
    const float* __restrict__ lng, const float* __restrict__ rg,
    float* __restrict__ yn) {
  const int lane = threadIdx.x & 63;
  const int gw = blockIdx.x * 4 + (threadIdx.x >> 6);  // (b*T+t)*8 + h
  const int h = gw & 7;
  const int bt = gw >> 3;
  float y = yb[(size_t)gw * 64 + lane];
  float s = y * y;
#pragma unroll
  for (int off = 32; off >= 1; off >>= 1) s += __shfl_xor(s, off);
  float r = rsqrtf(s * (1.0f / 64.0f) + 1e-6f);
  yn[(size_t)gw * 64 + lane] = y * r * (1.0f + lng[h * 64 + lane]) * rg[(size_t)bt * 8 + h];
}

// ---------------- launcher --------------------------------------------------
extern "C" void kernel_launch(void* const* d_in, const int* in_sizes, int n_in,
                              void* d_out, int out_size, void* d_ws, size_t ws_size,
                              hipStream_t stream) {
  (void)in_sizes; (void)n_in; (void)out_size; (void)ws_size;
  const float* x   = (const float*)d_in[0];
  const float* Wq  = (const float*)d_in[1];
  const float* Wk  = (const float*)d_in[2];
  const float* Wv  = (const float*)d_in[3];
  const float* Wpr = (const float*)d_in[4];
  const float* cqw = (const float*)d_in[5];
  const float* cqb = (const float*)d_in[6];
  const float* ckw = (const float*)d_in[7];
  const float* ckb = (const float*)d_in[8];
  const float* cvw = (const float*)d_in[9];
  const float* cvb = (const float*)d_in[10];
  const float* gaw = (const float*)d_in[11];
  const float* gab = (const float*)d_in[12];
  const float* gew = (const float*)d_in[13];
  const float* geb = (const float*)d_in[14];
  const float* gtw = (const float*)d_in[15];
  const float* gtb = (const float*)d_in[16];
  const float* ggw = (const float*)d_in[17];
  const float* ggb = (const float*)d_in[18];
  const float* pc  = (const float*)d_in[19];
  const float* lng = (const float*)d_in[20];
  const float* w1  = (const float*)d_in[21];
  const float* rgw = (const float*)d_in[22];
  float* outp = (float*)d_out;

  // ws layout (aliased to stay small):
  //   [0 .. 16MB)  chS (4M floats).  xq/xk/xv (1M floats each) alias its first
  //                12MB (dead before the chunk loop); yn aliases its start at the end.
  //   then qb,kb,vb,yb (4MB each), gates (5x64KB), Mc,Sc (256KB each)
  float* chS = (float*)d_ws;
  float* xq = chS;
  float* xk = chS + 1048576;
  float* xv = chS + 2 * 1048576;
  float* yn = chS;
  char* wp = (char*)d_ws + (size_t)16 * 1024 * 1024;
  auto alloc = [&](size_t bytes) {
    char* p = wp;
    wp += (bytes + 255) & ~(size_t)255;
    return p;
  };
  const size_t BT = (size_t)B_ * T_;  // 2048
  float* qb = (float*)alloc(BT * 512 * 4);
  float* kb = (float*)alloc(BT * 512 * 4);
  float* vb = (float*)alloc(BT * 512 * 4);
  float* yb = (float*)alloc(BT * 512 * 4);
  float* alpha = (float*)alloc(BT * 8 * 4);
  float* eta   = (float*)alloc(BT * 8 * 4);
  float* theta = (float*)alloc(BT * 8 * 4);
  float* gam   = (float*)alloc(BT * 8 * 4);
  float* rg    = (float*)alloc(BT * 8 * 4);
  float* Mc = (float*)alloc((size_t)65536 * 4);
  float* Sc = (float*)alloc((size_t)65536 * 4);

  init_carry<<<dim3(256), dim3(256), 0, stream>>>(w1, Mc, Sc);
  gemm_bt<<<dim3(32, 8), dim3(256), 0, stream>>>(x, Wq, xq, 2048, 512, 512);
  gemm_bt<<<dim3(32, 8), dim3(256), 0, stream>>>(x, Wk, xk, 2048, 512, 512);
  gemm_bt<<<dim3(32, 8), dim3(256), 0, stream>>>(x, Wv, xv, 2048, 512, 512);
  conv_k<<<dim3(4096), dim3(256), 0, stream>>>(xq, cqw, cqb, pc, qb);
  conv_k<<<dim3(4096), dim3(256), 0, stream>>>(xk, ckw, ckb, pc, kb);
  conv_k<<<dim3(4096), dim3(256), 0, stream>>>(xv, cvw, cvb, (const float*)nullptr, vb);
  gates_k<<<dim3(512), dim3(256), 0, stream>>>(x, gaw, gab, gew, geb, gtw, gtb,
                                               ggw, ggb, rgw, alpha, eta, theta, gam, rg);
  for (int ci = 0; ci < 16; ++ci) {
    chunk_a<<<dim3(256), dim3(256), 0, stream>>>(kb, vb, eta, theta, gam, Mc, Sc, chS, ci);
    polar_k<<<dim3(1024), dim3(256), 0, stream>>>(chS);
    chunk_c<<<dim3(256), dim3(256), 0, stream>>>(chS, alpha, qb, Mc, yb, ci);
  }
  norm_k<<<dim3(4096), dim3(256), 0, stream>>>(yb, lng, rg, yn);
  gemm_bt<<<dim3(32, 8), dim3(256), 0, stream>>>(yn, Wpr, outp, 2048, 512, 512);
}

// Round 3
// 1398.970 us; speedup vs baseline: 1.1939x; 1.1939x over previous
//
#include <hip/hip_runtime.h>

#define B_ 2
#define T_ 1024
#define H_ 8
#define D_ 64

typedef __attribute__((ext_vector_type(8))) short s8v;
typedef __attribute__((ext_vector_type(4))) short s4v;
typedef __attribute__((ext_vector_type(4))) float f4v;

__device__ __forceinline__ short f2bf(float f) {
  unsigned u = __float_as_uint(f);
  u += 0x7fffu + ((u >> 16) & 1u);
  return (short)(u >> 16);
}
__device__ __forceinline__ float bf2f(short s) {
  return __uint_as_float(((unsigned)(unsigned short)s) << 16);
}
__device__ __forceinline__ float sigm(float v) { return 1.0f / (1.0f + __expf(-v)); }

#define MFMA(a, b, c) __builtin_amdgcn_mfma_f32_16x16x32_bf16((a), (b), (c), 0, 0, 0)

// ---------------- GEMM: Co[M,N] = A[M,K] @ Bw[N,K]^T  (fp32 io, split-bf16) -
__global__ __launch_bounds__(256) void gemm_bt(const float* __restrict__ A,
    const float* __restrict__ Bw, float* __restrict__ Co,
    int M, int N, int K) {
  __shared__ short Ash[64][40], Asl[64][40];
  __shared__ short Bsh[64][40], Bsl[64][40];
  const int tid = threadIdx.x;
  const int lane = tid & 63;
  const int wv = tid >> 6;
  const int wr = (wv >> 1) * 32;
  const int wc = (wv & 1) * 32;
  const int m0 = blockIdx.x * 64;
  const int n0 = blockIdx.y * 64;
  const int ldr = tid >> 2;
  const int ldc = (tid & 3) * 8;
  const int l15 = lane & 15;
  const int kq = (lane >> 4) * 8;
  f4v acc[2][2];
#pragma unroll
  for (int i = 0; i < 2; ++i)
#pragma unroll
    for (int j = 0; j < 2; ++j)
#pragma unroll
      for (int r = 0; r < 4; ++r) acc[i][j][r] = 0.0f;
  const float* ap = A + (size_t)(m0 + ldr) * K + ldc;
  const float* bp = Bw + (size_t)(n0 + ldr) * K + ldc;
  for (int kt = 0; kt < K; kt += 32) {
    float4 av0 = *(const float4*)(ap + kt);
    float4 av1 = *(const float4*)(ap + kt + 4);
    float4 bv0 = *(const float4*)(bp + kt);
    float4 bv1 = *(const float4*)(bp + kt + 4);
    float af[8] = {av0.x, av0.y, av0.z, av0.w, av1.x, av1.y, av1.z, av1.w};
    float bf[8] = {bv0.x, bv0.y, bv0.z, bv0.w, bv1.x, bv1.y, bv1.z, bv1.w};
    s8v ah, al, bh, bl;
#pragma unroll
    for (int i = 0; i < 8; ++i) {
      short h = f2bf(af[i]); ah[i] = h; al[i] = f2bf(af[i] - bf2f(h));
      h = f2bf(bf[i]); bh[i] = h; bl[i] = f2bf(bf[i] - bf2f(h));
    }
    __syncthreads();
    *(s8v*)&Ash[ldr][ldc] = ah; *(s8v*)&Asl[ldr][ldc] = al;
    *(s8v*)&Bsh[ldr][ldc] = bh; *(s8v*)&Bsl[ldr][ldc] = bl;
    __syncthreads();
    s8v a0h = *(const s8v*)&Ash[wr + l15][kq];
    s8v a1h = *(const s8v*)&Ash[wr + 16 + l15][kq];
    s8v b0h = *(const s8v*)&Bsh[wc + l15][kq];
    s8v b1h = *(const s8v*)&Bsh[wc + 16 + l15][kq];
    s8v a0l = *(const s8v*)&Asl[wr + l15][kq];
    s8v a1l = *(const s8v*)&Asl[wr + 16 + l15][kq];
    s8v b0l = *(const s8v*)&Bsl[wc + l15][kq];
    s8v b1l = *(const s8v*)&Bsl[wc + 16 + l15][kq];
    acc[0][0] = MFMA(a0h, b0h, acc[0][0]);
    acc[0][1] = MFMA(a0h, b1h, acc[0][1]);
    acc[1][0] = MFMA(a1h, b0h, acc[1][0]);
    acc[1][1] = MFMA(a1h, b1h, acc[1][1]);
    acc[0][0] = MFMA(a0h, b0l, acc[0][0]);
    acc[0][1] = MFMA(a0h, b1l, acc[0][1]);
    acc[1][0] = MFMA(a1h, b0l, acc[1][0]);
    acc[1][1] = MFMA(a1h, b1l, acc[1][1]);
    acc[0][0] = MFMA(a0l, b0h, acc[0][0]);
    acc[0][1] = MFMA(a0l, b1h, acc[0][1]);
    acc[1][0] = MFMA(a1l, b0h, acc[1][0]);
    acc[1][1] = MFMA(a1l, b1h, acc[1][1]);
  }
#pragma unroll
  for (int m2 = 0; m2 < 2; ++m2)
#pragma unroll
    for (int n2 = 0; n2 < 2; ++n2)
#pragma unroll
      for (int r = 0; r < 4; ++r) {
        int row = m0 + wr + m2 * 16 + (lane >> 4) * 4 + r;
        int col = n0 + wc + n2 * 16 + l15;
        Co[(size_t)row * N + col] = acc[m2][n2][r];
      }
}

// ---------------- causal depthwise conv (K=4) + bias + phi scale ------------
__global__ __launch_bounds__(256) void conv_k(const float* __restrict__ in,
    const float* __restrict__ w, const float* __restrict__ bias,
    const float* __restrict__ pc, float* __restrict__ outp) {
  int idx = blockIdx.x * 256 + threadIdx.x;   // < B*T*512
  int d = idx & 511;
  int bt = idx >> 9;
  int t = bt & (T_ - 1);
  float acc = bias[d];
#pragma unroll
  for (int j = 0; j < 4; ++j) {
    int tt = t - 3 + j;
    if (tt >= 0) acc += w[d * 4 + j] * in[(size_t)(bt - 3 + j) * 512 + d];
  }
  float sc = pc ? pc[0] : 1.0f;
  outp[idx] = sc * acc;
}

// ---------------- gates: 5 x (B,T,H) sigmoid projections --------------------
__global__ __launch_bounds__(256) void gates_k(const float* __restrict__ x,
    const float* __restrict__ gaw, const float* __restrict__ gab,
    const float* __restrict__ gew, const float* __restrict__ geb,
    const float* __restrict__ gtw, const float* __restrict__ gtb,
    const float* __restrict__ ggw, const float* __restrict__ ggb,
    const float* __restrict__ rgw,
    float* __restrict__ alpha, float* __restrict__ eta,
    float* __restrict__ theta, float* __restrict__ gam, float* __restrict__ rg) {
  int wv = threadIdx.x >> 6, lane = threadIdx.x & 63;
  int bt = blockIdx.x * 4 + wv;   // < B*T
  float xr[8];
#pragma unroll
  for (int i = 0; i < 8; ++i) xr[i] = x[(size_t)bt * 512 + i * 64 + lane];
  for (int h = 0; h < 8; ++h) {
    float s0 = 0, s1 = 0, s2 = 0, s3 = 0, s4 = 0;
#pragma unroll
    for (int i = 0; i < 8; ++i) {
      float xv = xr[i];
      int o = h * 512 + i * 64 + lane;
      s0 += xv * gaw[o];
      s1 += xv * gew[o];
      s2 += xv * gtw[o];
      s3 += xv * ggw[o];
      s4 += xv * rgw[o];
    }
#pragma unroll
    for (int off = 32; off >= 1; off >>= 1) {
      s0 += __shfl_xor(s0, off);
      s1 += __shfl_xor(s1, off);
      s2 += __shfl_xor(s2, off);
      s3 += __shfl_xor(s3, off);
      s4 += __shfl_xor(s4, off);
    }
    if (lane == 0) {
      size_t o = (size_t)bt * 8 + h;
      alpha[o] = sigm(s0 + gab[h]);
      eta[o]   = 0.1f * sigm(s1 + geb[h]);
      theta[o] = sigm(s2 + gtb[h]);
      gam[o]   = sigm(s3 + ggb[h]);
      rg[o]    = sigm(s4);
    }
  }
}

// ---------------- init M/S carries ------------------------------------------
__global__ __launch_bounds__(256) void init_carry(const float* __restrict__ w1,
    float* __restrict__ Mc, float* __restrict__ Sc) {
  int idx = blockIdx.x * 256 + threadIdx.x;   // < 65536
  Mc[idx] = w1[idx & 32767];
  Sc[idx] = 0.0f;
}

// ---------------- bootstrap chunk_a (chunk 0): err -> omega -> S scan -------
__global__ __launch_bounds__(256) void chunk_a(
    const float* __restrict__ kb, const float* __restrict__ vb,
    const float* __restrict__ eta, const float* __restrict__ theta,
    const float* __restrict__ gam,
    const float* __restrict__ Mc, float* __restrict__ Sc,
    float* __restrict__ chS, int ci) {
  __shared__ float KT[64][65];   // KT[k][c]
  __shared__ float errl[4][68];  // err[vr][c]
  __shared__ float Ml[4][64];
  __shared__ float ge_[64], gt_[64], gg_[64];
  const int tid = threadIdx.x;
  const int bh = blockIdx.x >> 4;
  const int vs = blockIdx.x & 15;
  const int b = bh >> 3, h = bh & 7;
  const int v0 = vs * 4;
  const int t0 = ci * 64;
  const int lane = tid & 63, q4 = tid >> 6;
  for (int it = 0; it < 16; ++it) {
    int c = it * 4 + q4;
    KT[lane][c] = kb[((size_t)(b * T_ + t0 + c) * H_ + h) * 64 + lane];
  }
  if (tid < 64) {
    size_t gi = (size_t)(b * T_ + t0 + tid) * H_ + h;
    ge_[tid] = eta[gi]; gt_[tid] = theta[gi]; gg_[tid] = gam[gi];
  }
  Ml[q4][lane] = Mc[((size_t)bh * 64 + v0 + q4) * 64 + lane];
  __syncthreads();
  {
    int c = lane, vr = q4;
    float p = 0.0f;
#pragma unroll
    for (int k2 = 0; k2 < 64; ++k2) p += KT[k2][c] * Ml[vr][k2];
    float vv = vb[((size_t)(b * T_ + t0 + c) * H_ + h) * 64 + v0 + vr];
    errl[vr][c] = p - vv;
  }
  __syncthreads();
  {
    const int kk = lane, vr = q4, v = v0 + vr;
    float S = Sc[((size_t)bh * 64 + v) * 64 + kk];
    float ring[8];
    float cum = 0.0f;
    float* out = chS + ((size_t)(b << 6) * 8 + h) * 4096 + (size_t)v * 64 + kk;
    for (int c8 = 0; c8 < 8; ++c8) {
#pragma unroll
      for (int j = 0; j < 8; ++j) {
        int c = c8 * 8 + j;
        float u = 0.03125f * errl[vr][c] * KT[kk][c];
        float gu = gg_[c] * u;
        cum += gu;
        if (c8 > 0) cum -= ring[j];
        ring[j] = gu;
        float mom = -ge_[c] * cum;
        S = gt_[c] * S + mom;
        out[(size_t)c * 32768] = S;
      }
    }
    Sc[((size_t)bh * 64 + v) * 64 + kk] = S;
  }
}

// ---------------- split-precision 16x32-per-wave matmul (8 waves) -----------
__device__ __forceinline__ void mm8(const short (*Ah)[72], const short (*Al)[72],
    const short (*Bh)[72], const short (*Bl)[72],
    int wr, int wc, int l15, int kq, int sp, f4v acc[2]) {
#pragma unroll
  for (int kt = 0; kt < 64; kt += 32) {
    s8v ah = *(const s8v*)&Ah[wr + l15][kt + kq];
    s8v b0h = *(const s8v*)&Bh[wc + l15][kt + kq];
    s8v b1h = *(const s8v*)&Bh[wc + 16 + l15][kt + kq];
    acc[0] = MFMA(ah, b0h, acc[0]);
    acc[1] = MFMA(ah, b1h, acc[1]);
    if (sp) {
      s8v al_ = *(const s8v*)&Al[wr + l15][kt + kq];
      s8v b0l = *(const s8v*)&Bl[wc + l15][kt + kq];
      s8v b1l = *(const s8v*)&Bl[wc + 16 + l15][kt + kq];
      acc[0] = MFMA(ah, b0l, acc[0]);
      acc[1] = MFMA(ah, b1l, acc[1]);
      acc[0] = MFMA(al_, b0h, acc[0]);
      acc[1] = MFMA(al_, b1h, acc[1]);
    }
  }
}

// ---------------- polar express v2: X <- aX + X*(b*At + c*At^2), At = X^T X -
// All LDS stores are row-stores or symmetric transpose-stores; X kept in fp32
// registers across iterations. 8 waves, each owns a 16x32 output tile.
__global__ __launch_bounds__(512) void polar_k(float* __restrict__ cs) {
  __shared__ short Xh[64][72], Xl[64][72];     // X rows (hi/lo)
  __shared__ short XTh[64][72], XTl[64][72];   // X^T rows
  __shared__ short Zh[64][72], Zl[64][72];     // Atilde, then Ztilde (symmetric)
  __shared__ float red[8];
  const int tid = threadIdx.x;
  const int lane = tid & 63;
  const int wv = tid >> 6;          // 0..7
  const int wr = (wv >> 1) * 16;    // 0,16,32,48
  const int wc = (wv & 1) * 32;     // 0,32
  const int l15 = lane & 15;
  const int q4 = lane >> 4;
  const int kq = q4 * 8;
  const int rr0 = wr + q4 * 4;
  float* base = cs + (size_t)blockIdx.x * 4096;
  float xr[2][4];   // [n2][r]: element (rr0+r, wc+n2*16+l15)
  float ss = 0.0f;
#pragma unroll
  for (int n2 = 0; n2 < 2; ++n2)
#pragma unroll
    for (int r = 0; r < 4; ++r) {
      float v = base[(rr0 + r) * 64 + wc + n2 * 16 + l15];
      xr[n2][r] = v;
      ss += v * v;
    }
#pragma unroll
  for (int off = 32; off >= 1; off >>= 1) ss += __shfl_xor(ss, off);
  if (lane == 0) red[wv] = ss;
  __syncthreads();
  float tot = red[0] + red[1] + red[2] + red[3] + red[4] + red[5] + red[6] + red[7];
  float scale = 1.0f / (sqrtf(tot) * 1.01f + 1e-7f);
#pragma unroll
  for (int n2 = 0; n2 < 2; ++n2) {
    const int cc = wc + n2 * 16 + l15;
    s4v hv, lv;
#pragma unroll
    for (int r = 0; r < 4; ++r) {
      float xv = xr[n2][r] * scale;
      xr[n2][r] = xv;
      short hh = f2bf(xv);
      short ll = f2bf(xv - bf2f(hh));
      hv[r] = hh; lv[r] = ll;
      Xh[rr0 + r][cc] = hh;
      Xl[rr0 + r][cc] = ll;
    }
    *(s4v*)&XTh[cc][rr0] = hv;
    *(s4v*)&XTl[cc][rr0] = lv;
  }
  __syncthreads();

  for (int it = 0; it < 5; ++it) {
    const int sp = (it < 4);
    // ---- p1: Atilde = X^T X = mfma(XT, XT); store symmetric into Z ----
    f4v acc[2];
#pragma unroll
    for (int n2 = 0; n2 < 2; ++n2)
#pragma unroll
      for (int r = 0; r < 4; ++r) acc[n2][r] = 0.0f;
    mm8(XTh, XTl, XTh, XTl, wr, wc, l15, kq, sp, acc);
#pragma unroll
    for (int n2 = 0; n2 < 2; ++n2) {
      const int cc = wc + n2 * 16 + l15;
      s4v hv, lv;
#pragma unroll
      for (int r = 0; r < 4; ++r) {
        float a = acc[n2][r];
        short hh = f2bf(a);
        hv[r] = hh; lv[r] = f2bf(a - bf2f(hh));
      }
      *(s4v*)&Zh[cc][rr0] = hv;
      if (sp) *(s4v*)&Zl[cc][rr0] = lv;
    }
    __syncthreads();
    // ---- p2: A2 = mfma(Z, Z); Ztilde = b*At + c*A2; store symmetric ----
    f4v acc2[2];
#pragma unroll
    for (int n2 = 0; n2 < 2; ++n2)
#pragma unroll
      for (int r = 0; r < 4; ++r) acc2[n2][r] = 0.0f;
    mm8(Zh, Zl, Zh, Zl, wr, wc, l15, kq, sp, acc2);
    float zt[2][4];
#pragma unroll
    for (int n2 = 0; n2 < 2; ++n2) {
      const int cc = wc + n2 * 16 + l15;
      s4v zh4 = *(const s4v*)&Zh[cc][rr0];
      s4v zl4;
      if (sp) zl4 = *(const s4v*)&Zl[cc][rr0];
#pragma unroll
      for (int r = 0; r < 4; ++r) {
        float at = bf2f(zh4[r]) + (sp ? bf2f(zl4[r]) : 0.0f);
        zt[n2][r] = -4.7750f * at + 2.0315f * acc2[n2][r];
      }
    }
    __syncthreads();   // all reads of Z (mm + readback) complete
#pragma unroll
    for (int n2 = 0; n2 < 2; ++n2) {
      const int cc = wc + n2 * 16 + l15;
      s4v hv, lv;
#pragma unroll
      for (int r = 0; r < 4; ++r) {
        float zv = zt[n2][r];
        short hh = f2bf(zv);
        hv[r] = hh; lv[r] = f2bf(zv - bf2f(hh));
      }
      *(s4v*)&Zh[cc][rr0] = hv;
      if (sp) *(s4v*)&Zl[cc][rr0] = lv;
    }
    __syncthreads();
    // ---- p3: X_new = a*X + mfma(X, Ztilde) ----
    f4v acc3[2];
#pragma unroll
    for (int n2 = 0; n2 < 2; ++n2)
#pragma unroll
      for (int r = 0; r < 4; ++r) acc3[n2][r] = 0.0f;
    mm8(Xh, Xl, Zh, Zl, wr, wc, l15, kq, sp, acc3);
#pragma unroll
    for (int n2 = 0; n2 < 2; ++n2)
#pragma unroll
      for (int r = 0; r < 4; ++r)
        xr[n2][r] = 3.4445f * xr[n2][r] + acc3[n2][r];
    if (it < 4) {
      __syncthreads();   // all reads of X complete before overwrite
#pragma unroll
      for (int n2 = 0; n2 < 2; ++n2) {
        const int cc = wc + n2 * 16 + l15;
        s4v hv, lv;
#pragma unroll
        for (int r = 0; r < 4; ++r) {
          float xv = xr[n2][r];
          short hh = f2bf(xv);
          short ll = f2bf(xv - bf2f(hh));
          hv[r] = hh; lv[r] = ll;
          Xh[rr0 + r][cc] = hh;
          Xl[rr0 + r][cc] = ll;
        }
        *(s4v*)&XTh[cc][rr0] = hv;
        *(s4v*)&XTl[cc][rr0] = lv;
      }
      __syncthreads();
    }
  }
  // write back fp32 (in place)
#pragma unroll
  for (int n2 = 0; n2 < 2; ++n2)
#pragma unroll
    for (int r = 0; r < 4; ++r)
      base[(rr0 + r) * 64 + wc + n2 * 16 + l15] = xr[n2][r];
}

// ---------------- fused: chunk_c(ci) + chunk_a(ci+1) ------------------------
// block = (bh, vs); wave w owns v = vs*4 + w. Phase A reads chS rows v (all c);
// phase B overwrites exactly those rows for chunk ci+1 — block-local, safe.
__global__ __launch_bounds__(256) void chunk_ca(
    const float* __restrict__ qb, const float* __restrict__ kb,
    const float* __restrict__ vb,
    const float* __restrict__ alpha, const float* __restrict__ eta,
    const float* __restrict__ theta, const float* __restrict__ gam,
    float* __restrict__ Mc, float* __restrict__ Sc,
    float* __restrict__ chS, float* __restrict__ yb, int ci) {
  __shared__ float KT[64][65];
  __shared__ float errl[4][68];
  __shared__ float Ml[4][64];
  __shared__ float ge_[64], gt_[64], gg_[64];
  const int tid = threadIdx.x, lane = tid & 63, w = tid >> 6;
  const int bh = blockIdx.x >> 4, vs = blockIdx.x & 15;
  const int b = bh >> 3, h = bh & 7;
  const int v0 = vs * 4, v = v0 + w;
  const int t0 = ci * 64;
  float M = Mc[((size_t)bh * 64 + v) * 64 + lane];
  // ---- phase A: M-scan + y for chunk ci (depth-2 prefetch, dual reduce) ----
  const float* op = chS + ((size_t)(b << 6) * 8 + h) * 4096 + (size_t)v * 64 + lane;
  const float* qp = qb + ((size_t)(b * T_ + t0) * 8 + h) * 64 + lane;
  const float* ap = alpha + (size_t)(b * T_ + t0) * 8 + h;
  float* yp = yb + ((size_t)(b * T_ + t0) * 8 + h) * 64 + v;
  float o0 = op[0], o1 = op[32768];
  float q0 = qp[0], q1 = qp[512];
  float a0 = ap[0], a1 = ap[8];
  for (int c = 0; c < 64; c += 2) {
    float o2 = 0.f, o3 = 0.f, q2 = 0.f, q3 = 0.f, a2 = 0.f, a3 = 0.f;
    if (c < 62) {
      o2 = op[(size_t)(c + 2) * 32768]; o3 = op[(size_t)(c + 3) * 32768];
      q2 = qp[(c + 2) * 512];           q3 = qp[(c + 3) * 512];
      a2 = ap[(c + 2) * 8];             a3 = ap[(c + 3) * 8];
    }
    M = a0 * M + o0;
    float p0 = M * q0;
    M = a1 * M + o1;
    float p1 = M * q1;
#pragma unroll
    for (int off = 32; off >= 1; off >>= 1) {
      p0 += __shfl_xor(p0, off);
      p1 += __shfl_xor(p1, off);
    }
    if (lane == 0) {
      yp[(size_t)c * 512] = p0;
      yp[(size_t)(c + 1) * 512] = p1;
    }
    o0 = o2; o1 = o3; q0 = q2; q1 = q3; a0 = a2; a1 = a3;
  }
  Mc[((size_t)bh * 64 + v) * 64 + lane] = M;
  if (ci == 15) return;
  // ---- phase B: err + omega + S-scan for chunk ci+1 ----
  const int t1 = t0 + 64;
  Ml[w][lane] = M;
  for (int it = 0; it < 16; ++it) {
    int c = it * 4 + w;
    KT[lane][c] = kb[((size_t)(b * T_ + t1 + c) * 8 + h) * 64 + lane];
  }
  if (tid < 64) {
    size_t gi = (size_t)(b * T_ + t1 + tid) * 8 + h;
    ge_[tid] = eta[gi]; gt_[tid] = theta[gi]; gg_[tid] = gam[gi];
  }
  __syncthreads();
  {
    int c = lane, vr = w;
    float pr = 0.0f;
#pragma unroll
    for (int k2 = 0; k2 < 64; ++k2) pr += KT[k2][c] * Ml[vr][k2];
    float vv = vb[((size_t)(b * T_ + t1 + c) * 8 + h) * 64 + v0 + vr];
    errl[vr][c] = pr - vv;
  }
  __syncthreads();
  {
    const int kk = lane, vr = w, vv2 = v0 + vr;
    float S = Sc[((size_t)bh * 64 + vv2) * 64 + kk];
    float ring[8];
    float cum = 0.0f;
    float* out = chS + ((size_t)(b << 6) * 8 + h) * 4096 + (size_t)vv2 * 64 + kk;
    for (int c8 = 0; c8 < 8; ++c8) {
#pragma unroll
      for (int j = 0; j < 8; ++j) {
        int c = c8 * 8 + j;
        float u = 0.03125f * errl[vr][c] * KT[kk][c];
        float gu = gg_[c] * u;
        cum += gu;
        if (c8 > 0) cum -= ring[j];
        ring[j] = gu;
        float mom = -ge_[c] * cum;
        S = gt_[c] * S + mom;
        out[(size_t)c * 32768] = S;
      }
    }
    Sc[((size_t)bh * 64 + vv2) * 64 + kk] = S;
  }
}

// ---------------- RMS-norm * (1+ln_gamma) * rg ------------------------------
__global__ __launch_bounds__(256) void norm_k(const float* __restrict__ yb,
    const float* __restrict__ lng, const float* __restrict__ rg,
    float* __restrict__ yn) {
  const int lane = threadIdx.x & 63;
  const int gw = blockIdx.x * 4 + (threadIdx.x >> 6);  // (b*T+t)*8 + h
  const int h = gw & 7;
  const int bt = gw >> 3;
  float y = yb[(size_t)gw * 64 + lane];
  float s = y * y;
#pragma unroll
  for (int off = 32; off >= 1; off >>= 1) s += __shfl_xor(s, off);
  float r = rsqrtf(s * (1.0f / 64.0f) + 1e-6f);
  yn[(size_t)gw * 64 + lane] = y * r * (1.0f + lng[h * 64 + lane]) * rg[(size_t)bt * 8 + h];
}

// ---------------- launcher --------------------------------------------------
extern "C" void kernel_launch(void* const* d_in, const int* in_sizes, int n_in,
                              void* d_out, int out_size, void* d_ws, size_t ws_size,
                              hipStream_t stream) {
  (void)in_sizes; (void)n_in; (void)out_size; (void)ws_size;
  const float* x   = (const float*)d_in[0];
  const float* Wq  = (const float*)d_in[1];
  const float* Wk  = (const float*)d_in[2];
  const float* Wv  = (const float*)d_in[3];
  const float* Wpr = (const float*)d_in[4];
  const float* cqw = (const float*)d_in[5];
  const float* cqb = (const float*)d_in[6];
  const float* ckw = (const float*)d_in[7];
  const float* ckb = (const float*)d_in[8];
  const float* cvw = (const float*)d_in[9];
  const float* cvb = (const float*)d_in[10];
  const float* gaw = (const float*)d_in[11];
  const float* gab = (const float*)d_in[12];
  const float* gew = (const float*)d_in[13];
  const float* geb = (const float*)d_in[14];
  const float* gtw = (const float*)d_in[15];
  const float* gtb = (const float*)d_in[16];
  const float* ggw = (const float*)d_in[17];
  const float* ggb = (const float*)d_in[18];
  const float* pc  = (const float*)d_in[19];
  const float* lng = (const float*)d_in[20];
  const float* w1  = (const float*)d_in[21];
  const float* rgw = (const float*)d_in[22];
  float* outp = (float*)d_out;

  float* chS = (float*)d_ws;      // 16 MB (4M floats); xq/xk/xv/yn alias it
  float* xq = chS;
  float* xk = chS + 1048576;
  float* xv = chS + 2 * 1048576;
  float* yn = chS;
  char* wp = (char*)d_ws + (size_t)16 * 1024 * 1024;
  auto alloc = [&](size_t bytes) {
    char* p = wp;
    wp += (bytes + 255) & ~(size_t)255;
    return p;
  };
  const size_t BT = (size_t)B_ * T_;  // 2048
  float* qb = (float*)alloc(BT * 512 * 4);
  float* kb = (float*)alloc(BT * 512 * 4);
  float* vb = (float*)alloc(BT * 512 * 4);
  float* yb = (float*)alloc(BT * 512 * 4);
  float* alpha = (float*)alloc(BT * 8 * 4);
  float* eta   = (float*)alloc(BT * 8 * 4);
  float* theta = (float*)alloc(BT * 8 * 4);
  float* gam   = (float*)alloc(BT * 8 * 4);
  float* rg    = (float*)alloc(BT * 8 * 4);
  float* Mc = (float*)alloc((size_t)65536 * 4);
  float* Sc = (float*)alloc((size_t)65536 * 4);

  init_carry<<<dim3(256), dim3(256), 0, stream>>>(w1, Mc, Sc);
  gemm_bt<<<dim3(32, 8), dim3(256), 0, stream>>>(x, Wq, xq, 2048, 512, 512);
  gemm_bt<<<dim3(32, 8), dim3(256), 0, stream>>>(x, Wk, xk, 2048, 512, 512);
  gemm_bt<<<dim3(32, 8), dim3(256), 0, stream>>>(x, Wv, xv, 2048, 512, 512);
  conv_k<<<dim3(4096), dim3(256), 0, stream>>>(xq, cqw, cqb, pc, qb);
  conv_k<<<dim3(4096), dim3(256), 0, stream>>>(xk, ckw, ckb, pc, kb);
  conv_k<<<dim3(4096), dim3(256), 0, stream>>>(xv, cvw, cvb, (const float*)nullptr, vb);
  gates_k<<<dim3(512), dim3(256), 0, stream>>>(x, gaw, gab, gew, geb, gtw, gtb,
                                               ggw, ggb, rgw, alpha, eta, theta, gam, rg);
  chunk_a<<<dim3(256), dim3(256), 0, stream>>>(kb, vb, eta, theta, gam, Mc, Sc, chS, 0);
  for (int ci = 0; ci < 16; ++ci) {
    polar_k<<<dim3(1024), dim3(512), 0, stream>>>(chS);
    chunk_ca<<<dim3(256), dim3(256), 0, stream>>>(qb, kb, vb, alpha, eta, theta, gam,
                                                  Mc, Sc, chS, yb, ci);
  }
  norm_k<<<dim3(4096), dim3(256), 0, stream>>>(yb, lng, rg, yn);
  gemm_bt<<<dim3(32, 8), dim3(256), 0, stream>>>(yn, Wpr, outp, 2048, 512, 512);
}

// Round 4
// 1274.319 us; speedup vs baseline: 1.3106x; 1.0978x over previous
//
#include <hip/hip_runtime.h>

#define B_ 2
#define T_ 1024
#define H_ 8
#define D_ 64
#define PPAD 68

typedef __attribute__((ext_vector_type(8))) short s8v;
typedef __attribute__((ext_vector_type(4))) short s4v;
typedef __attribute__((ext_vector_type(4))) float f4v;

__device__ __forceinline__ short f2bf(float f) {
  unsigned u = __float_as_uint(f);
  u += 0x7fffu + ((u >> 16) & 1u);
  return (short)(u >> 16);
}
__device__ __forceinline__ float bf2f(short s) {
  return __uint_as_float(((unsigned)(unsigned short)s) << 16);
}
__device__ __forceinline__ float sigm(float v) { return 1.0f / (1.0f + __expf(-v)); }

#define MFMA(a, b, c) __builtin_amdgcn_mfma_f32_16x16x32_bf16((a), (b), (c), 0, 0, 0)

// ---------------- GEMM: Co[M,N] = A[M,K] @ Bw[N,K]^T  (fp32 io, split-bf16) -
__global__ __launch_bounds__(256) void gemm_bt(const float* __restrict__ A,
    const float* __restrict__ Bw, float* __restrict__ Co,
    int M, int N, int K) {
  __shared__ short Ash[64][40], Asl[64][40];
  __shared__ short Bsh[64][40], Bsl[64][40];
  const int tid = threadIdx.x;
  const int lane = tid & 63;
  const int wv = tid >> 6;
  const int wr = (wv >> 1) * 32;
  const int wc = (wv & 1) * 32;
  const int m0 = blockIdx.x * 64;
  const int n0 = blockIdx.y * 64;
  const int ldr = tid >> 2;
  const int ldc = (tid & 3) * 8;
  const int l15 = lane & 15;
  const int kq = (lane >> 4) * 8;
  f4v acc[2][2];
#pragma unroll
  for (int i = 0; i < 2; ++i)
#pragma unroll
    for (int j = 0; j < 2; ++j)
#pragma unroll
      for (int r = 0; r < 4; ++r) acc[i][j][r] = 0.0f;
  const float* ap = A + (size_t)(m0 + ldr) * K + ldc;
  const float* bp = Bw + (size_t)(n0 + ldr) * K + ldc;
  for (int kt = 0; kt < K; kt += 32) {
    float4 av0 = *(const float4*)(ap + kt);
    float4 av1 = *(const float4*)(ap + kt + 4);
    float4 bv0 = *(const float4*)(bp + kt);
    float4 bv1 = *(const float4*)(bp + kt + 4);
    float af[8] = {av0.x, av0.y, av0.z, av0.w, av1.x, av1.y, av1.z, av1.w};
    float bf[8] = {bv0.x, bv0.y, bv0.z, bv0.w, bv1.x, bv1.y, bv1.z, bv1.w};
    s8v ah, al, bh, bl;
#pragma unroll
    for (int i = 0; i < 8; ++i) {
      short h = f2bf(af[i]); ah[i] = h; al[i] = f2bf(af[i] - bf2f(h));
      h = f2bf(bf[i]); bh[i] = h; bl[i] = f2bf(bf[i] - bf2f(h));
    }
    __syncthreads();
    *(s8v*)&Ash[ldr][ldc] = ah; *(s8v*)&Asl[ldr][ldc] = al;
    *(s8v*)&Bsh[ldr][ldc] = bh; *(s8v*)&Bsl[ldr][ldc] = bl;
    __syncthreads();
    s8v a0h = *(const s8v*)&Ash[wr + l15][kq];
    s8v a1h = *(const s8v*)&Ash[wr + 16 + l15][kq];
    s8v b0h = *(const s8v*)&Bsh[wc + l15][kq];
    s8v b1h = *(const s8v*)&Bsh[wc + 16 + l15][kq];
    s8v a0l = *(const s8v*)&Asl[wr + l15][kq];
    s8v a1l = *(const s8v*)&Asl[wr + 16 + l15][kq];
    s8v b0l = *(const s8v*)&Bsl[wc + l15][kq];
    s8v b1l = *(const s8v*)&Bsl[wc + 16 + l15][kq];
    acc[0][0] = MFMA(a0h, b0h, acc[0][0]);
    acc[0][1] = MFMA(a0h, b1h, acc[0][1]);
    acc[1][0] = MFMA(a1h, b0h, acc[1][0]);
    acc[1][1] = MFMA(a1h, b1h, acc[1][1]);
    acc[0][0] = MFMA(a0h, b0l, acc[0][0]);
    acc[0][1] = MFMA(a0h, b1l, acc[0][1]);
    acc[1][0] = MFMA(a1h, b0l, acc[1][0]);
    acc[1][1] = MFMA(a1h, b1l, acc[1][1]);
    acc[0][0] = MFMA(a0l, b0h, acc[0][0]);
    acc[0][1] = MFMA(a0l, b1h, acc[0][1]);
    acc[1][0] = MFMA(a1l, b0h, acc[1][0]);
    acc[1][1] = MFMA(a1l, b1h, acc[1][1]);
  }
#pragma unroll
  for (int m2 = 0; m2 < 2; ++m2)
#pragma unroll
    for (int n2 = 0; n2 < 2; ++n2)
#pragma unroll
      for (int r = 0; r < 4; ++r) {
        int row = m0 + wr + m2 * 16 + (lane >> 4) * 4 + r;
        int col = n0 + wc + n2 * 16 + l15;
        Co[(size_t)row * N + col] = acc[m2][n2][r];
      }
}

// ---------------- fused q/k/v projection GEMM (one launch, 768 blocks) ------
__global__ __launch_bounds__(256) void gemm_qkv(const float* __restrict__ A,
    const float* __restrict__ Wq, const float* __restrict__ Wk,
    const float* __restrict__ Wv,
    float* __restrict__ xq, float* __restrict__ xk, float* __restrict__ xv) {
  __shared__ short Ash[64][40], Asl[64][40];
  __shared__ short Bsh[64][40], Bsl[64][40];
  const int sel = blockIdx.y >> 3;
  const float* Bw = sel == 0 ? Wq : (sel == 1 ? Wk : Wv);
  float* Co = sel == 0 ? xq : (sel == 1 ? xk : xv);
  const int tid = threadIdx.x;
  const int lane = tid & 63;
  const int wv = tid >> 6;
  const int wr = (wv >> 1) * 32;
  const int wc = (wv & 1) * 32;
  const int m0 = blockIdx.x * 64;
  const int n0 = (blockIdx.y & 7) * 64;
  const int ldr = tid >> 2;
  const int ldc = (tid & 3) * 8;
  const int l15 = lane & 15;
  const int kq = (lane >> 4) * 8;
  f4v acc[2][2];
#pragma unroll
  for (int i = 0; i < 2; ++i)
#pragma unroll
    for (int j = 0; j < 2; ++j)
#pragma unroll
      for (int r = 0; r < 4; ++r) acc[i][j][r] = 0.0f;
  const float* ap = A + (size_t)(m0 + ldr) * 512 + ldc;
  const float* bp = Bw + (size_t)(n0 + ldr) * 512 + ldc;
  for (int kt = 0; kt < 512; kt += 32) {
    float4 av0 = *(const float4*)(ap + kt);
    float4 av1 = *(const float4*)(ap + kt + 4);
    float4 bv0 = *(const float4*)(bp + kt);
    float4 bv1 = *(const float4*)(bp + kt + 4);
    float af[8] = {av0.x, av0.y, av0.z, av0.w, av1.x, av1.y, av1.z, av1.w};
    float bf[8] = {bv0.x, bv0.y, bv0.z, bv0.w, bv1.x, bv1.y, bv1.z, bv1.w};
    s8v ah, al, bh, bl;
#pragma unroll
    for (int i = 0; i < 8; ++i) {
      short h = f2bf(af[i]); ah[i] = h; al[i] = f2bf(af[i] - bf2f(h));
      h = f2bf(bf[i]); bh[i] = h; bl[i] = f2bf(bf[i] - bf2f(h));
    }
    __syncthreads();
    *(s8v*)&Ash[ldr][ldc] = ah; *(s8v*)&Asl[ldr][ldc] = al;
    *(s8v*)&Bsh[ldr][ldc] = bh; *(s8v*)&Bsl[ldr][ldc] = bl;
    __syncthreads();
    s8v a0h = *(const s8v*)&Ash[wr + l15][kq];
    s8v a1h = *(const s8v*)&Ash[wr + 16 + l15][kq];
    s8v b0h = *(const s8v*)&Bsh[wc + l15][kq];
    s8v b1h = *(const s8v*)&Bsh[wc + 16 + l15][kq];
    s8v a0l = *(const s8v*)&Asl[wr + l15][kq];
    s8v a1l = *(const s8v*)&Asl[wr + 16 + l15][kq];
    s8v b0l = *(const s8v*)&Bsl[wc + l15][kq];
    s8v b1l = *(const s8v*)&Bsl[wc + 16 + l15][kq];
    acc[0][0] = MFMA(a0h, b0h, acc[0][0]);
    acc[0][1] = MFMA(a0h, b1h, acc[0][1]);
    acc[1][0] = MFMA(a1h, b0h, acc[1][0]);
    acc[1][1] = MFMA(a1h, b1h, acc[1][1]);
    acc[0][0] = MFMA(a0h, b0l, acc[0][0]);
    acc[0][1] = MFMA(a0h, b1l, acc[0][1]);
    acc[1][0] = MFMA(a1h, b0l, acc[1][0]);
    acc[1][1] = MFMA(a1h, b1l, acc[1][1]);
    acc[0][0] = MFMA(a0l, b0h, acc[0][0]);
    acc[0][1] = MFMA(a0l, b1h, acc[0][1]);
    acc[1][0] = MFMA(a1l, b0h, acc[1][0]);
    acc[1][1] = MFMA(a1l, b1h, acc[1][1]);
  }
#pragma unroll
  for (int m2 = 0; m2 < 2; ++m2)
#pragma unroll
    for (int n2 = 0; n2 < 2; ++n2)
#pragma unroll
      for (int r = 0; r < 4; ++r) {
        int row = m0 + wr + m2 * 16 + (lane >> 4) * 4 + r;
        int col = n0 + wc + n2 * 16 + l15;
        Co[(size_t)row * 512 + col] = acc[m2][n2][r];
      }
}

// ---------------- fused causal depthwise conv for q,k,v ---------------------
__global__ __launch_bounds__(256) void conv3_k(
    const float* __restrict__ xq, const float* __restrict__ xk,
    const float* __restrict__ xv,
    const float* __restrict__ cqw, const float* __restrict__ cqb,
    const float* __restrict__ ckw, const float* __restrict__ ckb,
    const float* __restrict__ cvw, const float* __restrict__ cvb,
    const float* __restrict__ pc,
    float* __restrict__ qb, float* __restrict__ kb, float* __restrict__ vb) {
  const int s = blockIdx.x >> 12;                       // 0,1,2
  const int idx = ((blockIdx.x & 4095) << 8) + threadIdx.x;  // < 2048*512
  const float* in = s == 0 ? xq : (s == 1 ? xk : xv);
  const float* w  = s == 0 ? cqw : (s == 1 ? ckw : cvw);
  const float* bs = s == 0 ? cqb : (s == 1 ? ckb : cvb);
  float* o        = s == 0 ? qb : (s == 1 ? kb : vb);
  const int d = idx & 511;
  const int bt = idx >> 9;
  const int t = bt & (T_ - 1);
  float acc = bs[d];
#pragma unroll
  for (int j = 0; j < 4; ++j) {
    int tt = t - 3 + j;
    if (tt >= 0) acc += w[d * 4 + j] * in[(size_t)(bt - 3 + j) * 512 + d];
  }
  float sc = (s < 2) ? pc[0] : 1.0f;
  o[idx] = sc * acc;
}

// ---------------- gates: 5 x (B,T,H) sigmoid projections --------------------
__global__ __launch_bounds__(256) void gates_k(const float* __restrict__ x,
    const float* __restrict__ gaw, const float* __restrict__ gab,
    const float* __restrict__ gew, const float* __restrict__ geb,
    const float* __restrict__ gtw, const float* __restrict__ gtb,
    const float* __restrict__ ggw, const float* __restrict__ ggb,
    const float* __restrict__ rgw,
    float* __restrict__ alpha, float* __restrict__ eta,
    float* __restrict__ theta, float* __restrict__ gam, float* __restrict__ rg) {
  int wv = threadIdx.x >> 6, lane = threadIdx.x & 63;
  int bt = blockIdx.x * 4 + wv;   // < B*T
  float xr[8];
#pragma unroll
  for (int i = 0; i < 8; ++i) xr[i] = x[(size_t)bt * 512 + i * 64 + lane];
  for (int h = 0; h < 8; ++h) {
    float s0 = 0, s1 = 0, s2 = 0, s3 = 0, s4 = 0;
#pragma unroll
    for (int i = 0; i < 8; ++i) {
      float xv = xr[i];
      int o = h * 512 + i * 64 + lane;
      s0 += xv * gaw[o];
      s1 += xv * gew[o];
      s2 += xv * gtw[o];
      s3 += xv * ggw[o];
      s4 += xv * rgw[o];
    }
#pragma unroll
    for (int off = 32; off >= 1; off >>= 1) {
      s0 += __shfl_xor(s0, off);
      s1 += __shfl_xor(s1, off);
      s2 += __shfl_xor(s2, off);
      s3 += __shfl_xor(s3, off);
      s4 += __shfl_xor(s4, off);
    }
    if (lane == 0) {
      size_t o = (size_t)bt * 8 + h;
      alpha[o] = sigm(s0 + gab[h]);
      eta[o]   = 0.1f * sigm(s1 + geb[h]);
      theta[o] = sigm(s2 + gtb[h]);
      gam[o]   = sigm(s3 + ggb[h]);
      rg[o]    = sigm(s4);
    }
  }
}

// ---------------- init M/S carries ------------------------------------------
__global__ __launch_bounds__(256) void init_carry(const float* __restrict__ w1,
    float* __restrict__ Mc, float* __restrict__ Sc) {
  int idx = blockIdx.x * 256 + threadIdx.x;   // < 65536
  Mc[idx] = w1[idx & 32767];
  Sc[idx] = 0.0f;
}

// ---------------- bootstrap chunk_a (chunk 0): err -> omega -> S scan -------
__global__ __launch_bounds__(256) void chunk_a(
    const float* __restrict__ kb, const float* __restrict__ vb,
    const float* __restrict__ eta, const float* __restrict__ theta,
    const float* __restrict__ gam,
    const float* __restrict__ Mc, float* __restrict__ Sc,
    float* __restrict__ chS, int ci) {
  __shared__ float KT[64][65];   // KT[k][c]
  __shared__ float errl[4][68];  // err[vr][c]
  __shared__ float Ml[4][64];
  __shared__ float ge_[64], gt_[64], gg_[64];
  const int tid = threadIdx.x;
  const int bh = blockIdx.x >> 4;
  const int vs = blockIdx.x & 15;
  const int b = bh >> 3, h = bh & 7;
  const int v0 = vs * 4;
  const int t0 = ci * 64;
  const int lane = tid & 63, q4 = tid >> 6;
  for (int it = 0; it < 16; ++it) {
    int c = it * 4 + q4;
    KT[lane][c] = kb[((size_t)(b * T_ + t0 + c) * H_ + h) * 64 + lane];
  }
  if (tid < 64) {
    size_t gi = (size_t)(b * T_ + t0 + tid) * H_ + h;
    ge_[tid] = eta[gi]; gt_[tid] = theta[gi]; gg_[tid] = gam[gi];
  }
  Ml[q4][lane] = Mc[((size_t)bh * 64 + v0 + q4) * 64 + lane];
  __syncthreads();
  {
    int c = lane, vr = q4;
    float p = 0.0f;
#pragma unroll
    for (int k2 = 0; k2 < 64; ++k2) p += KT[k2][c] * Ml[vr][k2];
    float vv = vb[((size_t)(b * T_ + t0 + c) * H_ + h) * 64 + v0 + vr];
    errl[vr][c] = p - vv;
  }
  __syncthreads();
  {
    const int kk = lane, vr = q4, v = v0 + vr;
    float S = Sc[((size_t)bh * 64 + v) * 64 + kk];
    float ring[8];
    float cum = 0.0f;
    float* out = chS + ((size_t)(b << 6) * 8 + h) * 4096 + (size_t)v * 64 + kk;
    for (int c8 = 0; c8 < 8; ++c8) {
#pragma unroll
      for (int j = 0; j < 8; ++j) {
        int c = c8 * 8 + j;
        float u = 0.03125f * errl[vr][c] * KT[kk][c];
        float gu = gg_[c] * u;
        cum += gu;
        if (c8 > 0) cum -= ring[j];
        ring[j] = gu;
        float mom = -ge_[c] * cum;
        S = gt_[c] * S + mom;
        out[(size_t)c * 32768] = S;
      }
    }
    Sc[((size_t)bh * 64 + v) * 64 + kk] = S;
  }
}

// ---------------- 8B-aligned 8-element LDS load (pad 68 rows) ---------------
__device__ __forceinline__ s8v ld8(const short* p) {
  s4v lo = *(const s4v*)p;
  s4v hi = *(const s4v*)(p + 4);
  s8v r;
  r[0] = lo[0]; r[1] = lo[1]; r[2] = lo[2]; r[3] = lo[3];
  r[4] = hi[0]; r[5] = hi[1]; r[6] = hi[2]; r[7] = hi[3];
  return r;
}

// ---------------- split-precision 16x32-per-wave matmul (8 waves) -----------
__device__ __forceinline__ void mm8(const short (*Ah)[PPAD], const short (*Al)[PPAD],
    const short (*Bh)[PPAD], const short (*Bl)[PPAD],
    int wr, int wc, int l15, int kq, int sp, f4v acc[2]) {
#pragma unroll
  for (int kt = 0; kt < 64; kt += 32) {
    s8v ah = ld8(&Ah[wr + l15][kt + kq]);
    s8v b0h = ld8(&Bh[wc + l15][kt + kq]);
    s8v b1h = ld8(&Bh[wc + 16 + l15][kt + kq]);
    acc[0] = MFMA(ah, b0h, acc[0]);
    acc[1] = MFMA(ah, b1h, acc[1]);
    if (sp) {
      s8v al_ = ld8(&Al[wr + l15][kt + kq]);
      s8v b0l = ld8(&Bl[wc + l15][kt + kq]);
      s8v b1l = ld8(&Bl[wc + 16 + l15][kt + kq]);
      acc[0] = MFMA(ah, b0l, acc[0]);
      acc[1] = MFMA(ah, b1l, acc[1]);
      acc[0] = MFMA(al_, b0h, acc[0]);
      acc[1] = MFMA(al_, b1h, acc[1]);
    }
  }
}

// ---------------- polar express v3: X <- aX + X*(b*At + c*At^2), At = X^T X -
// At kept in registers between p1 and p2; pad 68 + b64 loads (bank-uniform);
// 52.2 KB LDS -> 3 blocks/CU.
__global__ __launch_bounds__(512, 6) void polar_k(float* __restrict__ cs) {
  __shared__ short Xh[64][PPAD], Xl[64][PPAD];     // X rows (hi/lo)
  __shared__ short XTh[64][PPAD], XTl[64][PPAD];   // X^T rows
  __shared__ short Zh[64][PPAD], Zl[64][PPAD];     // Atilde, then Ztilde
  __shared__ float red[8];
  const int tid = threadIdx.x;
  const int lane = tid & 63;
  const int wv = tid >> 6;          // 0..7
  const int wr = (wv >> 1) * 16;    // 0,16,32,48
  const int wc = (wv & 1) * 32;     // 0,32
  const int l15 = lane & 15;
  const int q4 = lane >> 4;
  const int kq = q4 * 8;
  const int rr0 = wr + q4 * 4;
  float* base = cs + (size_t)blockIdx.x * 4096;
  float xr[2][4];   // [n2][r]: element (rr0+r, wc+n2*16+l15)
  float ss = 0.0f;
#pragma unroll
  for (int n2 = 0; n2 < 2; ++n2)
#pragma unroll
    for (int r = 0; r < 4; ++r) {
      float v = base[(rr0 + r) * 64 + wc + n2 * 16 + l15];
      xr[n2][r] = v;
      ss += v * v;
    }
#pragma unroll
  for (int off = 32; off >= 1; off >>= 1) ss += __shfl_xor(ss, off);
  if (lane == 0) red[wv] = ss;
  __syncthreads();
  float tot = red[0] + red[1] + red[2] + red[3] + red[4] + red[5] + red[6] + red[7];
  float scale = 1.0f / (sqrtf(tot) * 1.01f + 1e-7f);
#pragma unroll
  for (int n2 = 0; n2 < 2; ++n2) {
    const int cc = wc + n2 * 16 + l15;
    s4v hv, lv;
#pragma unroll
    for (int r = 0; r < 4; ++r) {
      float xv = xr[n2][r] * scale;
      xr[n2][r] = xv;
      short hh = f2bf(xv);
      short ll = f2bf(xv - bf2f(hh));
      hv[r] = hh; lv[r] = ll;
      Xh[rr0 + r][cc] = hh;
      Xl[rr0 + r][cc] = ll;
    }
    *(s4v*)&XTh[cc][rr0] = hv;
    *(s4v*)&XTl[cc][rr0] = lv;
  }
  __syncthreads();

  for (int it = 0; it < 5; ++it) {
    const int sp = (it < 4);
    // ---- p1: At = X^T X = mm(XT, XT); At stays in regs; store sym into Z --
    f4v at[2];
#pragma unroll
    for (int n2 = 0; n2 < 2; ++n2)
#pragma unroll
      for (int r = 0; r < 4; ++r) at[n2][r] = 0.0f;
    mm8(XTh, XTl, XTh, XTl, wr, wc, l15, kq, sp, at);
#pragma unroll
    for (int n2 = 0; n2 < 2; ++n2) {
      const int cc = wc + n2 * 16 + l15;
      s4v hv, lv;
#pragma unroll
      for (int r = 0; r < 4; ++r) {
        float a = at[n2][r];
        short hh = f2bf(a);
        hv[r] = hh; lv[r] = f2bf(a - bf2f(hh));
      }
      *(s4v*)&Zh[cc][rr0] = hv;
      if (sp) *(s4v*)&Zl[cc][rr0] = lv;
    }
    __syncthreads();                       // publish At
    // ---- p2: A2 = mm(Z, Z); Zt = b*At + c*A2 (At from registers) ----
    f4v a2[2];
#pragma unroll
    for (int n2 = 0; n2 < 2; ++n2)
#pragma unroll
      for (int r = 0; r < 4; ++r) a2[n2][r] = 0.0f;
    mm8(Zh, Zl, Zh, Zl, wr, wc, l15, kq, sp, a2);
    float zt[2][4];
#pragma unroll
    for (int n2 = 0; n2 < 2; ++n2)
#pragma unroll
      for (int r = 0; r < 4; ++r)
        zt[n2][r] = -4.7750f * at[n2][r] + 2.0315f * a2[n2][r];
    __syncthreads();                       // all Z reads complete
#pragma unroll
    for (int n2 = 0; n2 < 2; ++n2) {
      const int cc = wc + n2 * 16 + l15;
      s4v hv, lv;
#pragma unroll
      for (int r = 0; r < 4; ++r) {
        float zv = zt[n2][r];
        short hh = f2bf(zv);
        hv[r] = hh; lv[r] = f2bf(zv - bf2f(hh));
      }
      *(s4v*)&Zh[cc][rr0] = hv;
      if (sp) *(s4v*)&Zl[cc][rr0] = lv;
    }
    __syncthreads();                       // publish Zt
    // ---- p3: X_new = a*X + mm(X, Zt) ----
    f4v q3[2];
#pragma unroll
    for (int n2 = 0; n2 < 2; ++n2)
#pragma unroll
      for (int r = 0; r < 4; ++r) q3[n2][r] = 0.0f;
    mm8(Xh, Xl, Zh, Zl, wr, wc, l15, kq, sp, q3);
#pragma unroll
    for (int n2 = 0; n2 < 2; ++n2)
#pragma unroll
      for (int r = 0; r < 4; ++r)
        xr[n2][r] = 3.4445f * xr[n2][r] + q3[n2][r];
    if (it < 4) {
      __syncthreads();                     // all X reads complete
      const int slo = (it < 3);            // next iter reads lo only if sp
#pragma unroll
      for (int n2 = 0; n2 < 2; ++n2) {
        const int cc = wc + n2 * 16 + l15;
        s4v hv, lv;
#pragma unroll
        for (int r = 0; r < 4; ++r) {
          float xv = xr[n2][r];
          short hh = f2bf(xv);
          short ll = f2bf(xv - bf2f(hh));
          hv[r] = hh; lv[r] = ll;
          Xh[rr0 + r][cc] = hh;
          if (slo) Xl[rr0 + r][cc] = ll;
        }
        *(s4v*)&XTh[cc][rr0] = hv;
        if (slo) *(s4v*)&XTl[cc][rr0] = lv;
      }
      __syncthreads();
    }
  }
  // write back fp32 (in place)
#pragma unroll
  for (int n2 = 0; n2 < 2; ++n2)
#pragma unroll
    for (int r = 0; r < 4; ++r)
      base[(rr0 + r) * 64 + wc + n2 * 16 + l15] = xr[n2][r];
}

// ---------------- fused: chunk_c(ci) + chunk_a(ci+1) ------------------------
__global__ __launch_bounds__(256) void chunk_ca(
    const float* __restrict__ qb, const float* __restrict__ kb,
    const float* __restrict__ vb,
    const float* __restrict__ alpha, const float* __restrict__ eta,
    const float* __restrict__ theta, const float* __restrict__ gam,
    float* __restrict__ Mc, float* __restrict__ Sc,
    float* __restrict__ chS, float* __restrict__ yb, int ci) {
  __shared__ float KT[64][65];
  __shared__ float errl[4][68];
  __shared__ float Ml[4][64];
  __shared__ float ge_[64], gt_[64], gg_[64];
  const int tid = threadIdx.x, lane = tid & 63, w = tid >> 6;
  const int bh = blockIdx.x >> 4, vs = blockIdx.x & 15;
  const int b = bh >> 3, h = bh & 7;
  const int v0 = vs * 4, v = v0 + w;
  const int t0 = ci * 64;
  float M = Mc[((size_t)bh * 64 + v) * 64 + lane];
  // ---- phase A: M-scan + y for chunk ci (depth-2 prefetch, dual reduce) ----
  const float* op = chS + ((size_t)(b << 6) * 8 + h) * 4096 + (size_t)v * 64 + lane;
  const float* qp = qb + ((size_t)(b * T_ + t0) * 8 + h) * 64 + lane;
  const float* ap = alpha + (size_t)(b * T_ + t0) * 8 + h;
  float* yp = yb + ((size_t)(b * T_ + t0) * 8 + h) * 64 + v;
  float o0 = op[0], o1 = op[32768];
  float q0 = qp[0], q1 = qp[512];
  float a0 = ap[0], a1 = ap[8];
  for (int c = 0; c < 64; c += 2) {
    float o2 = 0.f, o3 = 0.f, q2 = 0.f, q3 = 0.f, a2 = 0.f, a3 = 0.f;
    if (c < 62) {
      o2 = op[(size_t)(c + 2) * 32768]; o3 = op[(size_t)(c + 3) * 32768];
      q2 = qp[(c + 2) * 512];           q3 = qp[(c + 3) * 512];
      a2 = ap[(c + 2) * 8];             a3 = ap[(c + 3) * 8];
    }
    M = a0 * M + o0;
    float p0 = M * q0;
    M = a1 * M + o1;
    float p1 = M * q1;
#pragma unroll
    for (int off = 32; off >= 1; off >>= 1) {
      p0 += __shfl_xor(p0, off);
      p1 += __shfl_xor(p1, off);
    }
    if (lane == 0) {
      yp[(size_t)c * 512] = p0;
      yp[(size_t)(c + 1) * 512] = p1;
    }
    o0 = o2; o1 = o3; q0 = q2; q1 = q3; a0 = a2; a1 = a3;
  }
  Mc[((size_t)bh * 64 + v) * 64 + lane] = M;
  if (ci == 15) return;
  // ---- phase B: err + omega + S-scan for chunk ci+1 ----
  const int t1 = t0 + 64;
  Ml[w][lane] = M;
  for (int it = 0; it < 16; ++it) {
    int c = it * 4 + w;
    KT[lane][c] = kb[((size_t)(b * T_ + t1 + c) * 8 + h) * 64 + lane];
  }
  if (tid < 64) {
    size_t gi = (size_t)(b * T_ + t1 + tid) * 8 + h;
    ge_[tid] = eta[gi]; gt_[tid] = theta[gi]; gg_[tid] = gam[gi];
  }
  __syncthreads();
  {
    int c = lane, vr = w;
    float pr = 0.0f;
#pragma unroll
    for (int k2 = 0; k2 < 64; ++k2) pr += KT[k2][c] * Ml[vr][k2];
    float vv = vb[((size_t)(b * T_ + t1 + c) * 8 + h) * 64 + v0 + vr];
    errl[vr][c] = pr - vv;
  }
  __syncthreads();
  {
    const int kk = lane, vr = w, vv2 = v0 + vr;
    float S = Sc[((size_t)bh * 64 + vv2) * 64 + kk];
    float ring[8];
    float cum = 0.0f;
    float* out = chS + ((size_t)(b << 6) * 8 + h) * 4096 + (size_t)vv2 * 64 + kk;
    for (int c8 = 0; c8 < 8; ++c8) {
#pragma unroll
      for (int j = 0; j < 8; ++j) {
        int c = c8 * 8 + j;
        float u = 0.03125f * errl[vr][c] * KT[kk][c];
        float gu = gg_[c] * u;
        cum += gu;
        if (c8 > 0) cum -= ring[j];
        ring[j] = gu;
        float mom = -ge_[c] * cum;
        S = gt_[c] * S + mom;
        out[(size_t)c * 32768] = S;
      }
    }
    Sc[((size_t)bh * 64 + vv2) * 64 + kk] = S;
  }
}

// ---------------- RMS-norm * (1+ln_gamma) * rg ------------------------------
__global__ __launch_bounds__(256) void norm_k(const float* __restrict__ yb,
    const float* __restrict__ lng, const float* __restrict__ rg,
    float* __restrict__ yn) {
  const int lane = threadIdx.x & 63;
  const int gw = blockIdx.x * 4 + (threadIdx.x >> 6);  // (b*T+t)*8 + h
  const int h = gw & 7;
  const int bt = gw >> 3;
  float y = yb[(size_t)gw * 64 + lane];
  float s = y * y;
#pragma unroll
  for (int off = 32; off >= 1; off >>= 1) s += __shfl_xor(s, off);
  float r = rsqrtf(s * (1.0f / 64.0f) + 1e-6f);
  yn[(size_t)gw * 64 + lane] = y * r * (1.0f + lng[h * 64 + lane]) * rg[(size_t)bt * 8 + h];
}

// ---------------- launcher --------------------------------------------------
extern "C" void kernel_launch(void* const* d_in, const int* in_sizes, int n_in,
                              void* d_out, int out_size, void* d_ws, size_t ws_size,
                              hipStream_t stream) {
  (void)in_sizes; (void)n_in; (void)out_size; (void)ws_size;
  const float* x   = (const float*)d_in[0];
  const float* Wq  = (const float*)d_in[1];
  const float* Wk  = (const float*)d_in[2];
  const float* Wv  = (const float*)d_in[3];
  const float* Wpr = (const float*)d_in[4];
  const float* cqw = (const float*)d_in[5];
  const float* cqb = (const float*)d_in[6];
  const float* ckw = (const float*)d_in[7];
  const float* ckb = (const float*)d_in[8];
  const float* cvw = (const float*)d_in[9];
  const float* cvb = (const float*)d_in[10];
  const float* gaw = (const float*)d_in[11];
  const float* gab = (const float*)d_in[12];
  const float* gew = (const float*)d_in[13];
  const float* geb = (const float*)d_in[14];
  const float* gtw = (const float*)d_in[15];
  const float* gtb = (const float*)d_in[16];
  const float* ggw = (const float*)d_in[17];
  const float* ggb = (const float*)d_in[18];
  const float* pc  = (const float*)d_in[19];
  const float* lng = (const float*)d_in[20];
  const float* w1  = (const float*)d_in[21];
  const float* rgw = (const float*)d_in[22];
  float* outp = (float*)d_out;

  float* chS = (float*)d_ws;      // 16 MB (4M floats); xq/xk/xv/yn alias it
  float* xq = chS;
  float* xk = chS + 1048576;
  float* xv = chS + 2 * 1048576;
  float* yn = chS;
  char* wp = (char*)d_ws + (size_t)16 * 1024 * 1024;
  auto alloc = [&](size_t bytes) {
    char* p = wp;
    wp += (bytes + 255) & ~(size_t)255;
    return p;
  };
  const size_t BT = (size_t)B_ * T_;  // 2048
  float* qb = (float*)alloc(BT * 512 * 4);
  float* kb = (float*)alloc(BT * 512 * 4);
  float* vb = (float*)alloc(BT * 512 * 4);
  float* yb = (float*)alloc(BT * 512 * 4);
  float* alpha = (float*)alloc(BT * 8 * 4);
  float* eta   = (float*)alloc(BT * 8 * 4);
  float* theta = (float*)alloc(BT * 8 * 4);
  float* gam   = (float*)alloc(BT * 8 * 4);
  float* rg    = (float*)alloc(BT * 8 * 4);
  float* Mc = (float*)alloc((size_t)65536 * 4);
  float* Sc = (float*)alloc((size_t)65536 * 4);

  init_carry<<<dim3(256), dim3(256), 0, stream>>>(w1, Mc, Sc);
  gemm_qkv<<<dim3(32, 24), dim3(256), 0, stream>>>(x, Wq, Wk, Wv, xq, xk, xv);
  conv3_k<<<dim3(12288), dim3(256), 0, stream>>>(xq, xk, xv, cqw, cqb, ckw, ckb,
                                                 cvw, cvb, pc, qb, kb, vb);
  gates_k<<<dim3(512), dim3(256), 0, stream>>>(x, gaw, gab, gew, geb, gtw, gtb,
                                               ggw, ggb, rgw, alpha, eta, theta, gam, rg);
  chunk_a<<<dim3(256), dim3(256), 0, stream>>>(kb, vb, eta, theta, gam, Mc, Sc, chS, 0);
  for (int ci = 0; ci < 16; ++ci) {
    polar_k<<<dim3(1024), dim3(512), 0, stream>>>(chS);
    chunk_ca<<<dim3(256), dim3(256), 0, stream>>>(qb, kb, vb, alpha, eta, theta, gam,
                                                  Mc, Sc, chS, yb, ci);
  }
  norm_k<<<dim3(4096), dim3(256), 0, stream>>>(yb, lng, rg, yn);
  gemm_bt<<<dim3(32, 8), dim3(256), 0, stream>>>(yn, Wpr, outp, 2048, 512, 512);
}

// Round 5
// 1258.221 us; speedup vs baseline: 1.3274x; 1.0128x over previous
//
#include <hip/hip_runtime.h>

#define B_ 2
#define T_ 1024
#define H_ 8
#define D_ 64
#define PPAD 68

typedef __attribute__((ext_vector_type(8))) short s8v;
typedef __attribute__((ext_vector_type(4))) short s4v;
typedef __attribute__((ext_vector_type(4))) float f4v;

__device__ __forceinline__ short f2bf(float f) {
  unsigned u = __float_as_uint(f);
  u += 0x7fffu + ((u >> 16) & 1u);
  return (short)(u >> 16);
}
__device__ __forceinline__ float bf2f(short s) {
  return __uint_as_float(((unsigned)(unsigned short)s) << 16);
}
__device__ __forceinline__ float sigm(float v) { return 1.0f / (1.0f + __expf(-v)); }

#define MFMA(a, b, c) __builtin_amdgcn_mfma_f32_16x16x32_bf16((a), (b), (c), 0, 0, 0)

// ---------------- GEMM: Co[M,N] = A[M,K] @ Bw[N,K]^T  (fp32 io, split-bf16) -
__global__ __launch_bounds__(256) void gemm_bt(const float* __restrict__ A,
    const float* __restrict__ Bw, float* __restrict__ Co,
    int M, int N, int K) {
  __shared__ short Ash[64][40], Asl[64][40];
  __shared__ short Bsh[64][40], Bsl[64][40];
  const int tid = threadIdx.x;
  const int lane = tid & 63;
  const int wv = tid >> 6;
  const int wr = (wv >> 1) * 32;
  const int wc = (wv & 1) * 32;
  const int m0 = blockIdx.x * 64;
  const int n0 = blockIdx.y * 64;
  const int ldr = tid >> 2;
  const int ldc = (tid & 3) * 8;
  const int l15 = lane & 15;
  const int kq = (lane >> 4) * 8;
  f4v acc[2][2];
#pragma unroll
  for (int i = 0; i < 2; ++i)
#pragma unroll
    for (int j = 0; j < 2; ++j)
#pragma unroll
      for (int r = 0; r < 4; ++r) acc[i][j][r] = 0.0f;
  const float* ap = A + (size_t)(m0 + ldr) * K + ldc;
  const float* bp = Bw + (size_t)(n0 + ldr) * K + ldc;
  for (int kt = 0; kt < K; kt += 32) {
    float4 av0 = *(const float4*)(ap + kt);
    float4 av1 = *(const float4*)(ap + kt + 4);
    float4 bv0 = *(const float4*)(bp + kt);
    float4 bv1 = *(const float4*)(bp + kt + 4);
    float af[8] = {av0.x, av0.y, av0.z, av0.w, av1.x, av1.y, av1.z, av1.w};
    float bf[8] = {bv0.x, bv0.y, bv0.z, bv0.w, bv1.x, bv1.y, bv1.z, bv1.w};
    s8v ah, al, bh, bl;
#pragma unroll
    for (int i = 0; i < 8; ++i) {
      short h = f2bf(af[i]); ah[i] = h; al[i] = f2bf(af[i] - bf2f(h));
      h = f2bf(bf[i]); bh[i] = h; bl[i] = f2bf(bf[i] - bf2f(h));
    }
    __syncthreads();
    *(s8v*)&Ash[ldr][ldc] = ah; *(s8v*)&Asl[ldr][ldc] = al;
    *(s8v*)&Bsh[ldr][ldc] = bh; *(s8v*)&Bsl[ldr][ldc] = bl;
    __syncthreads();
    s8v a0h = *(const s8v*)&Ash[wr + l15][kq];
    s8v a1h = *(const s8v*)&Ash[wr + 16 + l15][kq];
    s8v b0h = *(const s8v*)&Bsh[wc + l15][kq];
    s8v b1h = *(const s8v*)&Bsh[wc + 16 + l15][kq];
    s8v a0l = *(const s8v*)&Asl[wr + l15][kq];
    s8v a1l = *(const s8v*)&Asl[wr + 16 + l15][kq];
    s8v b0l = *(const s8v*)&Bsl[wc + l15][kq];
    s8v b1l = *(const s8v*)&Bsl[wc + 16 + l15][kq];
    acc[0][0] = MFMA(a0h, b0h, acc[0][0]);
    acc[0][1] = MFMA(a0h, b1h, acc[0][1]);
    acc[1][0] = MFMA(a1h, b0h, acc[1][0]);
    acc[1][1] = MFMA(a1h, b1h, acc[1][1]);
    acc[0][0] = MFMA(a0h, b0l, acc[0][0]);
    acc[0][1] = MFMA(a0h, b1l, acc[0][1]);
    acc[1][0] = MFMA(a1h, b0l, acc[1][0]);
    acc[1][1] = MFMA(a1h, b1l, acc[1][1]);
    acc[0][0] = MFMA(a0l, b0h, acc[0][0]);
    acc[0][1] = MFMA(a0l, b1h, acc[0][1]);
    acc[1][0] = MFMA(a1l, b0h, acc[1][0]);
    acc[1][1] = MFMA(a1l, b1h, acc[1][1]);
  }
#pragma unroll
  for (int m2 = 0; m2 < 2; ++m2)
#pragma unroll
    for (int n2 = 0; n2 < 2; ++n2)
#pragma unroll
      for (int r = 0; r < 4; ++r) {
        int row = m0 + wr + m2 * 16 + (lane >> 4) * 4 + r;
        int col = n0 + wc + n2 * 16 + l15;
        Co[(size_t)row * N + col] = acc[m2][n2][r];
      }
}

// ---------------- fused q/k/v projection GEMM (one launch, 768 blocks) ------
__global__ __launch_bounds__(256) void gemm_qkv(const float* __restrict__ A,
    const float* __restrict__ Wq, const float* __restrict__ Wk,
    const float* __restrict__ Wv,
    float* __restrict__ xq, float* __restrict__ xk, float* __restrict__ xv) {
  __shared__ short Ash[64][40], Asl[64][40];
  __shared__ short Bsh[64][40], Bsl[64][40];
  const int sel = blockIdx.y >> 3;
  const float* Bw = sel == 0 ? Wq : (sel == 1 ? Wk : Wv);
  float* Co = sel == 0 ? xq : (sel == 1 ? xk : xv);
  const int tid = threadIdx.x;
  const int lane = tid & 63;
  const int wv = tid >> 6;
  const int wr = (wv >> 1) * 32;
  const int wc = (wv & 1) * 32;
  const int m0 = blockIdx.x * 64;
  const int n0 = (blockIdx.y & 7) * 64;
  const int ldr = tid >> 2;
  const int ldc = (tid & 3) * 8;
  const int l15 = lane & 15;
  const int kq = (lane >> 4) * 8;
  f4v acc[2][2];
#pragma unroll
  for (int i = 0; i < 2; ++i)
#pragma unroll
    for (int j = 0; j < 2; ++j)
#pragma unroll
      for (int r = 0; r < 4; ++r) acc[i][j][r] = 0.0f;
  const float* ap = A + (size_t)(m0 + ldr) * 512 + ldc;
  const float* bp = Bw + (size_t)(n0 + ldr) * 512 + ldc;
  for (int kt = 0; kt < 512; kt += 32) {
    float4 av0 = *(const float4*)(ap + kt);
    float4 av1 = *(const float4*)(ap + kt + 4);
    float4 bv0 = *(const float4*)(bp + kt);
    float4 bv1 = *(const float4*)(bp + kt + 4);
    float af[8] = {av0.x, av0.y, av0.z, av0.w, av1.x, av1.y, av1.z, av1.w};
    float bf[8] = {bv0.x, bv0.y, bv0.z, bv0.w, bv1.x, bv1.y, bv1.z, bv1.w};
    s8v ah, al, bh, bl;
#pragma unroll
    for (int i = 0; i < 8; ++i) {
      short h = f2bf(af[i]); ah[i] = h; al[i] = f2bf(af[i] - bf2f(h));
      h = f2bf(bf[i]); bh[i] = h; bl[i] = f2bf(bf[i] - bf2f(h));
    }
    __syncthreads();
    *(s8v*)&Ash[ldr][ldc] = ah; *(s8v*)&Asl[ldr][ldc] = al;
    *(s8v*)&Bsh[ldr][ldc] = bh; *(s8v*)&Bsl[ldr][ldc] = bl;
    __syncthreads();
    s8v a0h = *(const s8v*)&Ash[wr + l15][kq];
    s8v a1h = *(const s8v*)&Ash[wr + 16 + l15][kq];
    s8v b0h = *(const s8v*)&Bsh[wc + l15][kq];
    s8v b1h = *(const s8v*)&Bsh[wc + 16 + l15][kq];
    s8v a0l = *(const s8v*)&Asl[wr + l15][kq];
    s8v a1l = *(const s8v*)&Asl[wr + 16 + l15][kq];
    s8v b0l = *(const s8v*)&Bsl[wc + l15][kq];
    s8v b1l = *(const s8v*)&Bsl[wc + 16 + l15][kq];
    acc[0][0] = MFMA(a0h, b0h, acc[0][0]);
    acc[0][1] = MFMA(a0h, b1h, acc[0][1]);
    acc[1][0] = MFMA(a1h, b0h, acc[1][0]);
    acc[1][1] = MFMA(a1h, b1h, acc[1][1]);
    acc[0][0] = MFMA(a0h, b0l, acc[0][0]);
    acc[0][1] = MFMA(a0h, b1l, acc[0][1]);
    acc[1][0] = MFMA(a1h, b0l, acc[1][0]);
    acc[1][1] = MFMA(a1h, b1l, acc[1][1]);
    acc[0][0] = MFMA(a0l, b0h, acc[0][0]);
    acc[0][1] = MFMA(a0l, b1h, acc[0][1]);
    acc[1][0] = MFMA(a1l, b0h, acc[1][0]);
    acc[1][1] = MFMA(a1l, b1h, acc[1][1]);
  }
#pragma unroll
  for (int m2 = 0; m2 < 2; ++m2)
#pragma unroll
    for (int n2 = 0; n2 < 2; ++n2)
#pragma unroll
      for (int r = 0; r < 4; ++r) {
        int row = m0 + wr + m2 * 16 + (lane >> 4) * 4 + r;
        int col = n0 + wc + n2 * 16 + l15;
        Co[(size_t)row * 512 + col] = acc[m2][n2][r];
      }
}

// ---------------- fused causal depthwise conv for q,k,v ---------------------
__global__ __launch_bounds__(256) void conv3_k(
    const float* __restrict__ xq, const float* __restrict__ xk,
    const float* __restrict__ xv,
    const float* __restrict__ cqw, const float* __restrict__ cqb,
    const float* __restrict__ ckw, const float* __restrict__ ckb,
    const float* __restrict__ cvw, const float* __restrict__ cvb,
    const float* __restrict__ pc,
    float* __restrict__ qb, float* __restrict__ kb, float* __restrict__ vb) {
  const int s = blockIdx.x >> 12;                       // 0,1,2
  const int idx = ((blockIdx.x & 4095) << 8) + threadIdx.x;  // < 2048*512
  const float* in = s == 0 ? xq : (s == 1 ? xk : xv);
  const float* w  = s == 0 ? cqw : (s == 1 ? ckw : cvw);
  const float* bs = s == 0 ? cqb : (s == 1 ? ckb : cvb);
  float* o        = s == 0 ? qb : (s == 1 ? kb : vb);
  const int d = idx & 511;
  const int bt = idx >> 9;
  const int t = bt & (T_ - 1);
  float acc = bs[d];
#pragma unroll
  for (int j = 0; j < 4; ++j) {
    int tt = t - 3 + j;
    if (tt >= 0) acc += w[d * 4 + j] * in[(size_t)(bt - 3 + j) * 512 + d];
  }
  float sc = (s < 2) ? pc[0] : 1.0f;
  o[idx] = sc * acc;
}

// ---------------- gates: 5 x (B,T,H) sigmoid projections --------------------
__global__ __launch_bounds__(256) void gates_k(const float* __restrict__ x,
    const float* __restrict__ gaw, const float* __restrict__ gab,
    const float* __restrict__ gew, const float* __restrict__ geb,
    const float* __restrict__ gtw, const float* __restrict__ gtb,
    const float* __restrict__ ggw, const float* __restrict__ ggb,
    const float* __restrict__ rgw,
    float* __restrict__ alpha, float* __restrict__ eta,
    float* __restrict__ theta, float* __restrict__ gam, float* __restrict__ rg) {
  int wv = threadIdx.x >> 6, lane = threadIdx.x & 63;
  int bt = blockIdx.x * 4 + wv;   // < B*T
  float xr[8];
#pragma unroll
  for (int i = 0; i < 8; ++i) xr[i] = x[(size_t)bt * 512 + i * 64 + lane];
  for (int h = 0; h < 8; ++h) {
    float s0 = 0, s1 = 0, s2 = 0, s3 = 0, s4 = 0;
#pragma unroll
    for (int i = 0; i < 8; ++i) {
      float xv = xr[i];
      int o = h * 512 + i * 64 + lane;
      s0 += xv * gaw[o];
      s1 += xv * gew[o];
      s2 += xv * gtw[o];
      s3 += xv * ggw[o];
      s4 += xv * rgw[o];
    }
#pragma unroll
    for (int off = 32; off >= 1; off >>= 1) {
      s0 += __shfl_xor(s0, off);
      s1 += __shfl_xor(s1, off);
      s2 += __shfl_xor(s2, off);
      s3 += __shfl_xor(s3, off);
      s4 += __shfl_xor(s4, off);
    }
    if (lane == 0) {
      size_t o = (size_t)bt * 8 + h;
      alpha[o] = sigm(s0 + gab[h]);
      eta[o]   = 0.1f * sigm(s1 + geb[h]);
      theta[o] = sigm(s2 + gtb[h]);
      gam[o]   = sigm(s3 + ggb[h]);
      rg[o]    = sigm(s4);
    }
  }
}

// ---------------- init M/S carries ------------------------------------------
__global__ __launch_bounds__(256) void init_carry(const float* __restrict__ w1,
    float* __restrict__ Mc, float* __restrict__ Sc) {
  int idx = blockIdx.x * 256 + threadIdx.x;   // < 65536
  Mc[idx] = w1[idx & 32767];
  Sc[idx] = 0.0f;
}

// ---------------- bootstrap chunk_a (chunk 0): err -> omega -> S scan -------
__global__ __launch_bounds__(256) void chunk_a(
    const float* __restrict__ kb, const float* __restrict__ vb,
    const float* __restrict__ eta, const float* __restrict__ theta,
    const float* __restrict__ gam,
    const float* __restrict__ Mc, float* __restrict__ Sc,
    float* __restrict__ chS, int ci) {
  __shared__ float KT[64][65];   // KT[k][c]
  __shared__ float errl[4][68];  // err[vr][c]
  __shared__ float Ml[4][64];
  __shared__ float ge_[64], gt_[64], gg_[64];
  const int tid = threadIdx.x;
  const int bh = blockIdx.x >> 4;
  const int vs = blockIdx.x & 15;
  const int b = bh >> 3, h = bh & 7;
  const int v0 = vs * 4;
  const int t0 = ci * 64;
  const int lane = tid & 63, q4 = tid >> 6;
  for (int it = 0; it < 16; ++it) {
    int c = it * 4 + q4;
    KT[lane][c] = kb[((size_t)(b * T_ + t0 + c) * H_ + h) * 64 + lane];
  }
  if (tid < 64) {
    size_t gi = (size_t)(b * T_ + t0 + tid) * H_ + h;
    ge_[tid] = eta[gi]; gt_[tid] = theta[gi]; gg_[tid] = gam[gi];
  }
  Ml[q4][lane] = Mc[((size_t)bh * 64 + v0 + q4) * 64 + lane];
  __syncthreads();
  {
    int c = lane, vr = q4;
    float p = 0.0f;
#pragma unroll
    for (int k2 = 0; k2 < 64; ++k2) p += KT[k2][c] * Ml[vr][k2];
    float vv = vb[((size_t)(b * T_ + t0 + c) * H_ + h) * 64 + v0 + vr];
    errl[vr][c] = p - vv;
  }
  __syncthreads();
  {
    const int kk = lane, vr = q4, v = v0 + vr;
    float S = Sc[((size_t)bh * 64 + v) * 64 + kk];
    float ring[8];
    float cum = 0.0f;
    float* out = chS + ((size_t)(b << 6) * 8 + h) * 4096 + (size_t)v * 64 + kk;
    for (int c8 = 0; c8 < 8; ++c8) {
#pragma unroll
      for (int j = 0; j < 8; ++j) {
        int c = c8 * 8 + j;
        float u = 0.03125f * errl[vr][c] * KT[kk][c];
        float gu = gg_[c] * u;
        cum += gu;
        if (c8 > 0) cum -= ring[j];
        ring[j] = gu;
        float mom = -ge_[c] * cum;
        S = gt_[c] * S + mom;
        out[(size_t)c * 32768] = S;
      }
    }
    Sc[((size_t)bh * 64 + v) * 64 + kk] = S;
  }
}

// ---------------- 8B-aligned 8-element LDS load (pad 68 rows) ---------------
__device__ __forceinline__ s8v ld8(const short* p) {
  s4v lo = *(const s4v*)p;
  s4v hi = *(const s4v*)(p + 4);
  s8v r;
  r[0] = lo[0]; r[1] = lo[1]; r[2] = lo[2]; r[3] = lo[3];
  r[4] = hi[0]; r[5] = hi[1]; r[6] = hi[2]; r[7] = hi[3];
  return r;
}

// ---------------- split-precision 32x32-per-wave matmul (4 waves) -----------
__device__ __forceinline__ void mm4(const short (*Ah)[PPAD], const short (*Al)[PPAD],
    const short (*Bh)[PPAD], const short (*Bl)[PPAD],
    int wr, int wc, int l15, int kq, int sp, f4v acc[2][2]) {
#pragma unroll
  for (int kt = 0; kt < 64; kt += 32) {
    s8v a0h = ld8(&Ah[wr + l15][kt + kq]);
    s8v a1h = ld8(&Ah[wr + 16 + l15][kt + kq]);
    s8v b0h = ld8(&Bh[wc + l15][kt + kq]);
    s8v b1h = ld8(&Bh[wc + 16 + l15][kt + kq]);
    acc[0][0] = MFMA(a0h, b0h, acc[0][0]);
    acc[0][1] = MFMA(a0h, b1h, acc[0][1]);
    acc[1][0] = MFMA(a1h, b0h, acc[1][0]);
    acc[1][1] = MFMA(a1h, b1h, acc[1][1]);
    if (sp) {
      s8v a0l = ld8(&Al[wr + l15][kt + kq]);
      s8v a1l = ld8(&Al[wr + 16 + l15][kt + kq]);
      s8v b0l = ld8(&Bl[wc + l15][kt + kq]);
      s8v b1l = ld8(&Bl[wc + 16 + l15][kt + kq]);
      acc[0][0] = MFMA(a0h, b0l, acc[0][0]);
      acc[0][1] = MFMA(a0h, b1l, acc[0][1]);
      acc[1][0] = MFMA(a1h, b0l, acc[1][0]);
      acc[1][1] = MFMA(a1h, b1l, acc[1][1]);
      acc[0][0] = MFMA(a0l, b0h, acc[0][0]);
      acc[0][1] = MFMA(a0l, b1h, acc[0][1]);
      acc[1][0] = MFMA(a1l, b0h, acc[1][0]);
      acc[1][1] = MFMA(a1l, b1h, acc[1][1]);
    }
  }
}

// ---------------- polar express v4: 4 waves, 32x32 tile per wave ------------
// X <- aX + X*(b*At + c*At^2), At = X^T X; At held in registers p1->p2;
// all LDS stores row-wise or symmetric-transposed; 52 KB LDS -> 3 blocks/CU.
__global__ __launch_bounds__(256, 3) void polar_k(float* __restrict__ cs) {
  __shared__ short Xh[64][PPAD], Xl[64][PPAD];     // X rows (hi/lo)
  __shared__ short XTh[64][PPAD], XTl[64][PPAD];   // X^T rows
  __shared__ short Zh[64][PPAD], Zl[64][PPAD];     // At, then Zt (symmetric)
  __shared__ float red[4];
  const int tid = threadIdx.x;
  const int lane = tid & 63;
  const int w = tid >> 6;           // 0..3
  const int wr = (w >> 1) * 32;     // 0,32
  const int wc = (w & 1) * 32;      // 0,32
  const int l15 = lane & 15;
  const int q4 = lane >> 4;
  const int kq = q4 * 8;
  float* base = cs + (size_t)blockIdx.x * 4096;
  float xr[2][2][4];   // [m2][n2][r]: element (wr+m2*16+q4*4+r, wc+n2*16+l15)
  float ss = 0.0f;
#pragma unroll
  for (int m2 = 0; m2 < 2; ++m2)
#pragma unroll
    for (int n2 = 0; n2 < 2; ++n2)
#pragma unroll
      for (int r = 0; r < 4; ++r) {
        float v = base[(wr + m2 * 16 + q4 * 4 + r) * 64 + wc + n2 * 16 + l15];
        xr[m2][n2][r] = v;
        ss += v * v;
      }
#pragma unroll
  for (int off = 32; off >= 1; off >>= 1) ss += __shfl_xor(ss, off);
  if (lane == 0) red[w] = ss;
  __syncthreads();
  float scale = 1.0f / (sqrtf(red[0] + red[1] + red[2] + red[3]) * 1.01f + 1e-7f);
#pragma unroll
  for (int m2 = 0; m2 < 2; ++m2)
#pragma unroll
    for (int n2 = 0; n2 < 2; ++n2) {
      const int rr0 = wr + m2 * 16 + q4 * 4;
      const int cc = wc + n2 * 16 + l15;
      s4v hv, lv;
#pragma unroll
      for (int r = 0; r < 4; ++r) {
        float xv = xr[m2][n2][r] * scale;
        xr[m2][n2][r] = xv;
        short hh = f2bf(xv);
        short ll = f2bf(xv - bf2f(hh));
        hv[r] = hh; lv[r] = ll;
        Xh[rr0 + r][cc] = hh;
        Xl[rr0 + r][cc] = ll;
      }
      *(s4v*)&XTh[cc][rr0] = hv;
      *(s4v*)&XTl[cc][rr0] = lv;
    }
  __syncthreads();

  for (int it = 0; it < 5; ++it) {
    const int sp = (it < 4);
    // ---- p1: At = X^T X = mm(XT,XT); At stays in regs; store sym into Z ---
    f4v at[2][2];
#pragma unroll
    for (int m2 = 0; m2 < 2; ++m2)
#pragma unroll
      for (int n2 = 0; n2 < 2; ++n2)
#pragma unroll
        for (int r = 0; r < 4; ++r) at[m2][n2][r] = 0.0f;
    mm4(XTh, XTl, XTh, XTl, wr, wc, l15, kq, sp, at);
#pragma unroll
    for (int m2 = 0; m2 < 2; ++m2)
#pragma unroll
      for (int n2 = 0; n2 < 2; ++n2) {
        const int rr0 = wr + m2 * 16 + q4 * 4;
        const int cc = wc + n2 * 16 + l15;
        s4v hv, lv;
#pragma unroll
        for (int r = 0; r < 4; ++r) {
          float a = at[m2][n2][r];
          short hh = f2bf(a);
          hv[r] = hh; lv[r] = f2bf(a - bf2f(hh));
        }
        *(s4v*)&Zh[cc][rr0] = hv;
        if (sp) *(s4v*)&Zl[cc][rr0] = lv;
      }
    __syncthreads();                       // publish At
    // ---- p2: A2 = mm(Z,Z); Zt = b*At + c*A2 (At from registers) ----
    f4v a2[2][2];
#pragma unroll
    for (int m2 = 0; m2 < 2; ++m2)
#pragma unroll
      for (int n2 = 0; n2 < 2; ++n2)
#pragma unroll
        for (int r = 0; r < 4; ++r) a2[m2][n2][r] = 0.0f;
    mm4(Zh, Zl, Zh, Zl, wr, wc, l15, kq, sp, a2);
    float zt[2][2][4];
#pragma unroll
    for (int m2 = 0; m2 < 2; ++m2)
#pragma unroll
      for (int n2 = 0; n2 < 2; ++n2)
#pragma unroll
        for (int r = 0; r < 4; ++r)
          zt[m2][n2][r] = -4.7750f * at[m2][n2][r] + 2.0315f * a2[m2][n2][r];
    __syncthreads();                       // all Z reads complete
#pragma unroll
    for (int m2 = 0; m2 < 2; ++m2)
#pragma unroll
      for (int n2 = 0; n2 < 2; ++n2) {
        const int rr0 = wr + m2 * 16 + q4 * 4;
        const int cc = wc + n2 * 16 + l15;
        s4v hv, lv;
#pragma unroll
        for (int r = 0; r < 4; ++r) {
          float zv = zt[m2][n2][r];
          short hh = f2bf(zv);
          hv[r] = hh; lv[r] = f2bf(zv - bf2f(hh));
        }
        *(s4v*)&Zh[cc][rr0] = hv;
        if (sp) *(s4v*)&Zl[cc][rr0] = lv;
      }
    __syncthreads();                       // publish Zt
    // ---- p3: X_new = a*X + mm(X, Zt) ----
    f4v q3[2][2];
#pragma unroll
    for (int m2 = 0; m2 < 2; ++m2)
#pragma unroll
      for (int n2 = 0; n2 < 2; ++n2)
#pragma unroll
        for (int r = 0; r < 4; ++r) q3[m2][n2][r] = 0.0f;
    mm4(Xh, Xl, Zh, Zl, wr, wc, l15, kq, sp, q3);
#pragma unroll
    for (int m2 = 0; m2 < 2; ++m2)
#pragma unroll
      for (int n2 = 0; n2 < 2; ++n2)
#pragma unroll
        for (int r = 0; r < 4; ++r)
          xr[m2][n2][r] = 3.4445f * xr[m2][n2][r] + q3[m2][n2][r];
    if (it < 4) {
      __syncthreads();                     // all X reads complete
      const int slo = (it < 3);            // next iter reads lo only if split
#pragma unroll
      for (int m2 = 0; m2 < 2; ++m2)
#pragma unroll
        for (int n2 = 0; n2 < 2; ++n2) {
          const int rr0 = wr + m2 * 16 + q4 * 4;
          const int cc = wc + n2 * 16 + l15;
          s4v hv, lv;
#pragma unroll
          for (int r = 0; r < 4; ++r) {
            float xv = xr[m2][n2][r];
            short hh = f2bf(xv);
            short ll = f2bf(xv - bf2f(hh));
            hv[r] = hh; lv[r] = ll;
            Xh[rr0 + r][cc] = hh;
            if (slo) Xl[rr0 + r][cc] = ll;
          }
          *(s4v*)&XTh[cc][rr0] = hv;
          if (slo) *(s4v*)&XTl[cc][rr0] = lv;
        }
      __syncthreads();
    }
  }
  // write back fp32 (in place)
#pragma unroll
  for (int m2 = 0; m2 < 2; ++m2)
#pragma unroll
    for (int n2 = 0; n2 < 2; ++n2)
#pragma unroll
      for (int r = 0; r < 4; ++r)
        base[(wr + m2 * 16 + q4 * 4 + r) * 64 + wc + n2 * 16 + l15] = xr[m2][n2][r];
}

// ---------------- fused: chunk_c(ci) + chunk_a(ci+1) ------------------------
// Phase A: full register staging — all 64 o/q loads issued up-front, alpha
// broadcast from lanes; the scan is a pure 64-FMA chain + pipelined reduces.
__global__ __launch_bounds__(256, 1) void chunk_ca(
    const float* __restrict__ qb, const float* __restrict__ kb,
    const float* __restrict__ vb,
    const float* __restrict__ alpha, const float* __restrict__ eta,
    const float* __restrict__ theta, const float* __restrict__ gam,
    float* __restrict__ Mc, float* __restrict__ Sc,
    float* __restrict__ chS, float* __restrict__ yb, int ci) {
  __shared__ float KT[64][65];
  __shared__ float errl[4][68];
  __shared__ float Ml[4][64];
  __shared__ float ge_[64], gt_[64], gg_[64];
  const int tid = threadIdx.x, lane = tid & 63, w = tid >> 6;
  const int bh = blockIdx.x >> 4, vs = blockIdx.x & 15;
  const int b = bh >> 3, h = bh & 7;
  const int v0 = vs * 4, v = v0 + w;
  const int t0 = ci * 64;
  float M = Mc[((size_t)bh * 64 + v) * 64 + lane];
  // ---- phase A ----
  const float* op = chS + ((size_t)(b << 6) * 8 + h) * 4096 + (size_t)v * 64 + lane;
  const float* qp = qb + ((size_t)(b * T_ + t0) * 8 + h) * 64 + lane;
  float* yp = yb + ((size_t)(b * T_ + t0) * 8 + h) * 64 + v;
  float av = alpha[(size_t)(b * T_ + t0 + lane) * 8 + h];
  float ov[64], qv[64];
#pragma unroll
  for (int c = 0; c < 64; ++c) ov[c] = op[(size_t)c * 32768];
#pragma unroll
  for (int c = 0; c < 64; ++c) qv[c] = qp[(size_t)c * 512];
#pragma unroll
  for (int c = 0; c < 64; ++c) {
    M = __builtin_fmaf(__shfl(av, c), M, ov[c]);
    float p = M * qv[c];
#pragma unroll
    for (int off = 32; off >= 1; off >>= 1) p += __shfl_xor(p, off);
    if (lane == 0) yp[(size_t)c * 512] = p;
  }
  Mc[((size_t)bh * 64 + v) * 64 + lane] = M;
  if (ci == 15) return;
  // ---- phase B: err + omega + S-scan for chunk ci+1 ----
  const int t1 = t0 + 64;
  Ml[w][lane] = M;
  for (int it = 0; it < 16; ++it) {
    int c = it * 4 + w;
    KT[lane][c] = kb[((size_t)(b * T_ + t1 + c) * 8 + h) * 64 + lane];
  }
  if (tid < 64) {
    size_t gi = (size_t)(b * T_ + t1 + tid) * 8 + h;
    ge_[tid] = eta[gi]; gt_[tid] = theta[gi]; gg_[tid] = gam[gi];
  }
  __syncthreads();
  {
    int c = lane, vr = w;
    float pr = 0.0f;
#pragma unroll
    for (int k2 = 0; k2 < 64; ++k2) pr += KT[k2][c] * Ml[vr][k2];
    float vv = vb[((size_t)(b * T_ + t1 + c) * 8 + h) * 64 + v0 + vr];
    errl[vr][c] = pr - vv;
  }
  __syncthreads();
  {
    const int kk = lane, vr = w, vv2 = v0 + vr;
    float S = Sc[((size_t)bh * 64 + vv2) * 64 + kk];
    float ring[8];
    float cum = 0.0f;
    float* out = chS + ((size_t)(b << 6) * 8 + h) * 4096 + (size_t)vv2 * 64 + kk;
    for (int c8 = 0; c8 < 8; ++c8) {
#pragma unroll
      for (int j = 0; j < 8; ++j) {
        int c = c8 * 8 + j;
        float u = 0.03125f * errl[vr][c] * KT[kk][c];
        float gu = gg_[c] * u;
        cum += gu;
        if (c8 > 0) cum -= ring[j];
        ring[j] = gu;
        float mom = -ge_[c] * cum;
        S = gt_[c] * S + mom;
        out[(size_t)c * 32768] = S;
      }
    }
    Sc[((size_t)bh * 64 + vv2) * 64 + kk] = S;
  }
}

// ---------------- RMS-norm * (1+ln_gamma) * rg ------------------------------
__global__ __launch_bounds__(256) void norm_k(const float* __restrict__ yb,
    const float* __restrict__ lng, const float* __restrict__ rg,
    float* __restrict__ yn) {
  const int lane = threadIdx.x & 63;
  const int gw = blockIdx.x * 4 + (threadIdx.x >> 6);  // (b*T+t)*8 + h
  const int h = gw & 7;
  const int bt = gw >> 3;
  float y = yb[(size_t)gw * 64 + lane];
  float s = y * y;
#pragma unroll
  for (int off = 32; off >= 1; off >>= 1) s += __shfl_xor(s, off);
  float r = rsqrtf(s * (1.0f / 64.0f) + 1e-6f);
  yn[(size_t)gw * 64 + lane] = y * r * (1.0f + lng[h * 64 + lane]) * rg[(size_t)bt * 8 + h];
}

// ---------------- launcher --------------------------------------------------
extern "C" void kernel_launch(void* const* d_in, const int* in_sizes, int n_in,
                              void* d_out, int out_size, void* d_ws, size_t ws_size,
                              hipStream_t stream) {
  (void)in_sizes; (void)n_in; (void)out_size; (void)ws_size;
  const float* x   = (const float*)d_in[0];
  const float* Wq  = (const float*)d_in[1];
  const float* Wk  = (const float*)d_in[2];
  const float* Wv  = (const float*)d_in[3];
  const float* Wpr = (const float*)d_in[4];
  const float* cqw = (const float*)d_in[5];
  const float* cqb = (const float*)d_in[6];
  const float* ckw = (const float*)d_in[7];
  const float* ckb = (const float*)d_in[8];
  const float* cvw = (const float*)d_in[9];
  const float* cvb = (const float*)d_in[10];
  const float* gaw = (const float*)d_in[11];
  const float* gab = (const float*)d_in[12];
  const float* gew = (const float*)d_in[13];
  const float* geb = (const float*)d_in[14];
  const float* gtw = (const float*)d_in[15];
  const float* gtb = (const float*)d_in[16];
  const float* ggw = (const float*)d_in[17];
  const float* ggb = (const float*)d_in[18];
  const float* pc  = (const float*)d_in[19];
  const float* lng = (const float*)d_in[20];
  const float* w1  = (const float*)d_in[21];
  const float* rgw = (const float*)d_in[22];
  float* outp = (float*)d_out;

  float* chS = (float*)d_ws;      // 16 MB (4M floats); xq/xk/xv/yn alias it
  float* xq = chS;
  float* xk = chS + 1048576;
  float* xv = chS + 2 * 1048576;
  float* yn = chS;
  char* wp = (char*)d_ws + (size_t)16 * 1024 * 1024;
  auto alloc = [&](size_t bytes) {
    char* p = wp;
    wp += (bytes + 255) & ~(size_t)255;
    return p;
  };
  const size_t BT = (size_t)B_ * T_;  // 2048
  float* qb = (float*)alloc(BT * 512 * 4);
  float* kb = (float*)alloc(BT * 512 * 4);
  float* vb = (float*)alloc(BT * 512 * 4);
  float* yb = (float*)alloc(BT * 512 * 4);
  float* alpha = (float*)alloc(BT * 8 * 4);
  float* eta   = (float*)alloc(BT * 8 * 4);
  float* theta = (float*)alloc(BT * 8 * 4);
  float* gam   = (float*)alloc(BT * 8 * 4);
  float* rg    = (float*)alloc(BT * 8 * 4);
  float* Mc = (float*)alloc((size_t)65536 * 4);
  float* Sc = (float*)alloc((size_t)65536 * 4);

  init_carry<<<dim3(256), dim3(256), 0, stream>>>(w1, Mc, Sc);
  gemm_qkv<<<dim3(32, 24), dim3(256), 0, stream>>>(x, Wq, Wk, Wv, xq, xk, xv);
  conv3_k<<<dim3(12288), dim3(256), 0, stream>>>(xq, xk, xv, cqw, cqb, ckw, ckb,
                                                 cvw, cvb, pc, qb, kb, vb);
  gates_k<<<dim3(512), dim3(256), 0, stream>>>(x, gaw, gab, gew, geb, gtw, gtb,
                                               ggw, ggb, rgw, alpha, eta, theta, gam, rg);
  chunk_a<<<dim3(256), dim3(256), 0, stream>>>(kb, vb, eta, theta, gam, Mc, Sc, chS, 0);
  for (int ci = 0; ci < 16; ++ci) {
    polar_k<<<dim3(1024), dim3(256), 0, stream>>>(chS);
    chunk_ca<<<dim3(256), dim3(256), 0, stream>>>(qb, kb, vb, alpha, eta, theta, gam,
                                                  Mc, Sc, chS, yb, ci);
  }
  norm_k<<<dim3(4096), dim3(256), 0, stream>>>(yb, lng, rg, yn);
  gemm_bt<<<dim3(32, 8), dim3(256), 0, stream>>>(yn, Wpr, outp, 2048, 512, 512);
}

// Round 7
// 1033.293 us; speedup vs baseline: 1.6164x; 1.2177x over previous
//
#include <hip/hip_runtime.h>

#define B_ 2
#define T_ 1024
#define H_ 8
#define D_ 64
// XOR swizzle: element (r,c) lives at [r][c ^ ((r&7)<<3)]; preserves 8-short
// (16B) group alignment so b128 reads and s4v stores stay legal.
#define SW(r, c) ((c) ^ (((r) & 7) << 3))

typedef __attribute__((ext_vector_type(8))) short s8v;
typedef __attribute__((ext_vector_type(4))) short s4v;
typedef __attribute__((ext_vector_type(4))) float f4v;

__device__ __forceinline__ short f2bf(float f) {
  unsigned u = __float_as_uint(f);
  u += 0x7fffu + ((u >> 16) & 1u);
  return (short)(u >> 16);
}
__device__ __forceinline__ float bf2f(short s) {
  return __uint_as_float(((unsigned)(unsigned short)s) << 16);
}
__device__ __forceinline__ float sigm(float v) { return 1.0f / (1.0f + __expf(-v)); }

#define MFMA(a, b, c) __builtin_amdgcn_mfma_f32_16x16x32_bf16((a), (b), (c), 0, 0, 0)

// ---------------- GEMM: Co[M,N] = A[M,K] @ Bw[N,K]^T  (fp32 io, split-bf16) -
__global__ __launch_bounds__(256) void gemm_bt(const float* __restrict__ A,
    const float* __restrict__ Bw, float* __restrict__ Co,
    int M, int N, int K) {
  __shared__ short Ash[64][40], Asl[64][40];
  __shared__ short Bsh[64][40], Bsl[64][40];
  const int tid = threadIdx.x;
  const int lane = tid & 63;
  const int wv = tid >> 6;
  const int wr = (wv >> 1) * 32;
  const int wc = (wv & 1) * 32;
  const int m0 = blockIdx.x * 64;
  const int n0 = blockIdx.y * 64;
  const int ldr = tid >> 2;
  const int ldc = (tid & 3) * 8;
  const int l15 = lane & 15;
  const int kq = (lane >> 4) * 8;
  f4v acc[2][2];
#pragma unroll
  for (int i = 0; i < 2; ++i)
#pragma unroll
    for (int j = 0; j < 2; ++j)
#pragma unroll
      for (int r = 0; r < 4; ++r) acc[i][j][r] = 0.0f;
  const float* ap = A + (size_t)(m0 + ldr) * K + ldc;
  const float* bp = Bw + (size_t)(n0 + ldr) * K + ldc;
  for (int kt = 0; kt < K; kt += 32) {
    float4 av0 = *(const float4*)(ap + kt);
    float4 av1 = *(const float4*)(ap + kt + 4);
    float4 bv0 = *(const float4*)(bp + kt);
    float4 bv1 = *(const float4*)(bp + kt + 4);
    float af[8] = {av0.x, av0.y, av0.z, av0.w, av1.x, av1.y, av1.z, av1.w};
    float bf[8] = {bv0.x, bv0.y, bv0.z, bv0.w, bv1.x, bv1.y, bv1.z, bv1.w};
    s8v ah, al, bh, bl;
#pragma unroll
    for (int i = 0; i < 8; ++i) {
      short h = f2bf(af[i]); ah[i] = h; al[i] = f2bf(af[i] - bf2f(h));
      h = f2bf(bf[i]); bh[i] = h; bl[i] = f2bf(bf[i] - bf2f(h));
    }
    __syncthreads();
    *(s8v*)&Ash[ldr][ldc] = ah; *(s8v*)&Asl[ldr][ldc] = al;
    *(s8v*)&Bsh[ldr][ldc] = bh; *(s8v*)&Bsl[ldr][ldc] = bl;
    __syncthreads();
    s8v a0h = *(const s8v*)&Ash[wr + l15][kq];
    s8v a1h = *(const s8v*)&Ash[wr + 16 + l15][kq];
    s8v b0h = *(const s8v*)&Bsh[wc + l15][kq];
    s8v b1h = *(const s8v*)&Bsh[wc + 16 + l15][kq];
    s8v a0l = *(const s8v*)&Asl[wr + l15][kq];
    s8v a1l = *(const s8v*)&Asl[wr + 16 + l15][kq];
    s8v b0l = *(const s8v*)&Bsl[wc + l15][kq];
    s8v b1l = *(const s8v*)&Bsl[wc + 16 + l15][kq];
    acc[0][0] = MFMA(a0h, b0h, acc[0][0]);
    acc[0][1] = MFMA(a0h, b1h, acc[0][1]);
    acc[1][0] = MFMA(a1h, b0h, acc[1][0]);
    acc[1][1] = MFMA(a1h, b1h, acc[1][1]);
    acc[0][0] = MFMA(a0h, b0l, acc[0][0]);
    acc[0][1] = MFMA(a0h, b1l, acc[0][1]);
    acc[1][0] = MFMA(a1h, b0l, acc[1][0]);
    acc[1][1] = MFMA(a1h, b1l, acc[1][1]);
    acc[0][0] = MFMA(a0l, b0h, acc[0][0]);
    acc[0][1] = MFMA(a0l, b1h, acc[0][1]);
    acc[1][0] = MFMA(a1l, b0h, acc[1][0]);
    acc[1][1] = MFMA(a1l, b1h, acc[1][1]);
  }
#pragma unroll
  for (int m2 = 0; m2 < 2; ++m2)
#pragma unroll
    for (int n2 = 0; n2 < 2; ++n2)
#pragma unroll
      for (int r = 0; r < 4; ++r) {
        int row = m0 + wr + m2 * 16 + (lane >> 4) * 4 + r;
        int col = n0 + wc + n2 * 16 + l15;
        Co[(size_t)row * N + col] = acc[m2][n2][r];
      }
}

// ---------------- fused q/k/v projection GEMM (one launch, 768 blocks) ------
__global__ __launch_bounds__(256) void gemm_qkv(const float* __restrict__ A,
    const float* __restrict__ Wq, const float* __restrict__ Wk,
    const float* __restrict__ Wv,
    float* __restrict__ xq, float* __restrict__ xk, float* __restrict__ xv) {
  __shared__ short Ash[64][40], Asl[64][40];
  __shared__ short Bsh[64][40], Bsl[64][40];
  const int sel = blockIdx.y >> 3;
  const float* Bw = sel == 0 ? Wq : (sel == 1 ? Wk : Wv);
  float* Co = sel == 0 ? xq : (sel == 1 ? xk : xv);
  const int tid = threadIdx.x;
  const int lane = tid & 63;
  const int wv = tid >> 6;
  const int wr = (wv >> 1) * 32;
  const int wc = (wv & 1) * 32;
  const int m0 = blockIdx.x * 64;
  const int n0 = (blockIdx.y & 7) * 64;
  const int ldr = tid >> 2;
  const int ldc = (tid & 3) * 8;
  const int l15 = lane & 15;
  const int kq = (lane >> 4) * 8;
  f4v acc[2][2];
#pragma unroll
  for (int i = 0; i < 2; ++i)
#pragma unroll
    for (int j = 0; j < 2; ++j)
#pragma unroll
      for (int r = 0; r < 4; ++r) acc[i][j][r] = 0.0f;
  const float* ap = A + (size_t)(m0 + ldr) * 512 + ldc;
  const float* bp = Bw + (size_t)(n0 + ldr) * 512 + ldc;
  for (int kt = 0; kt < 512; kt += 32) {
    float4 av0 = *(const float4*)(ap + kt);
    float4 av1 = *(const float4*)(ap + kt + 4);
    float4 bv0 = *(const float4*)(bp + kt);
    float4 bv1 = *(const float4*)(bp + kt + 4);
    float af[8] = {av0.x, av0.y, av0.z, av0.w, av1.x, av1.y, av1.z, av1.w};
    float bf[8] = {bv0.x, bv0.y, bv0.z, bv0.w, bv1.x, bv1.y, bv1.z, bv1.w};
    s8v ah, al, bh, bl;
#pragma unroll
    for (int i = 0; i < 8; ++i) {
      short h = f2bf(af[i]); ah[i] = h; al[i] = f2bf(af[i] - bf2f(h));
      h = f2bf(bf[i]); bh[i] = h; bl[i] = f2bf(bf[i] - bf2f(h));
    }
    __syncthreads();
    *(s8v*)&Ash[ldr][ldc] = ah; *(s8v*)&Asl[ldr][ldc] = al;
    *(s8v*)&Bsh[ldr][ldc] = bh; *(s8v*)&Bsl[ldr][ldc] = bl;
    __syncthreads();
    s8v a0h = *(const s8v*)&Ash[wr + l15][kq];
    s8v a1h = *(const s8v*)&Ash[wr + 16 + l15][kq];
    s8v b0h = *(const s8v*)&Bsh[wc + l15][kq];
    s8v b1h = *(const s8v*)&Bsh[wc + 16 + l15][kq];
    s8v a0l = *(const s8v*)&Asl[wr + l15][kq];
    s8v a1l = *(const s8v*)&Asl[wr + 16 + l15][kq];
    s8v b0l = *(const s8v*)&Bsl[wc + l15][kq];
    s8v b1l = *(const s8v*)&Bsl[wc + 16 + l15][kq];
    acc[0][0] = MFMA(a0h, b0h, acc[0][0]);
    acc[0][1] = MFMA(a0h, b1h, acc[0][1]);
    acc[1][0] = MFMA(a1h, b0h, acc[1][0]);
    acc[1][1] = MFMA(a1h, b1h, acc[1][1]);
    acc[0][0] = MFMA(a0h, b0l, acc[0][0]);
    acc[0][1] = MFMA(a0h, b1l, acc[0][1]);
    acc[1][0] = MFMA(a1h, b0l, acc[1][0]);
    acc[1][1] = MFMA(a1h, b1l, acc[1][1]);
    acc[0][0] = MFMA(a0l, b0h, acc[0][0]);
    acc[0][1] = MFMA(a0l, b1h, acc[0][1]);
    acc[1][0] = MFMA(a1l, b0h, acc[1][0]);
    acc[1][1] = MFMA(a1l, b1h, acc[1][1]);
  }
#pragma unroll
  for (int m2 = 0; m2 < 2; ++m2)
#pragma unroll
    for (int n2 = 0; n2 < 2; ++n2)
#pragma unroll
      for (int r = 0; r < 4; ++r) {
        int row = m0 + wr + m2 * 16 + (lane >> 4) * 4 + r;
        int col = n0 + wc + n2 * 16 + l15;
        Co[(size_t)row * 512 + col] = acc[m2][n2][r];
      }
}

// ---------------- fused causal depthwise conv for q,k,v ---------------------
__global__ __launch_bounds__(256) void conv3_k(
    const float* __restrict__ xq, const float* __restrict__ xk,
    const float* __restrict__ xv,
    const float* __restrict__ cqw, const float* __restrict__ cqb,
    const float* __restrict__ ckw, const float* __restrict__ ckb,
    const float* __restrict__ cvw, const float* __restrict__ cvb,
    const float* __restrict__ pc,
    float* __restrict__ qb, float* __restrict__ kb, float* __restrict__ vb) {
  const int s = blockIdx.x >> 12;                       // 0,1,2
  const int idx = ((blockIdx.x & 4095) << 8) + threadIdx.x;  // < 2048*512
  const float* in = s == 0 ? xq : (s == 1 ? xk : xv);
  const float* w  = s == 0 ? cqw : (s == 1 ? ckw : cvw);
  const float* bs = s == 0 ? cqb : (s == 1 ? ckb : cvb);
  float* o        = s == 0 ? qb : (s == 1 ? kb : vb);
  const int d = idx & 511;
  const int bt = idx >> 9;
  const int t = bt & (T_ - 1);
  float acc = bs[d];
#pragma unroll
  for (int j = 0; j < 4; ++j) {
    int tt = t - 3 + j;
    if (tt >= 0) acc += w[d * 4 + j] * in[(size_t)(bt - 3 + j) * 512 + d];
  }
  float sc = (s < 2) ? pc[0] : 1.0f;
  o[idx] = sc * acc;
}

// ---------------- gates: 5 x (B,T,H) sigmoid projections --------------------
__global__ __launch_bounds__(256) void gates_k(const float* __restrict__ x,
    const float* __restrict__ gaw, const float* __restrict__ gab,
    const float* __restrict__ gew, const float* __restrict__ geb,
    const float* __restrict__ gtw, const float* __restrict__ gtb,
    const float* __restrict__ ggw, const float* __restrict__ ggb,
    const float* __restrict__ rgw,
    float* __restrict__ alpha, float* __restrict__ eta,
    float* __restrict__ theta, float* __restrict__ gam, float* __restrict__ rg) {
  int wv = threadIdx.x >> 6, lane = threadIdx.x & 63;
  int bt = blockIdx.x * 4 + wv;   // < B*T
  float xr[8];
#pragma unroll
  for (int i = 0; i < 8; ++i) xr[i] = x[(size_t)bt * 512 + i * 64 + lane];
  for (int h = 0; h < 8; ++h) {
    float s0 = 0, s1 = 0, s2 = 0, s3 = 0, s4 = 0;
#pragma unroll
    for (int i = 0; i < 8; ++i) {
      float xv = xr[i];
      int o = h * 512 + i * 64 + lane;
      s0 += xv * gaw[o];
      s1 += xv * gew[o];
      s2 += xv * gtw[o];
      s3 += xv * ggw[o];
      s4 += xv * rgw[o];
    }
#pragma unroll
    for (int off = 32; off >= 1; off >>= 1) {
      s0 += __shfl_xor(s0, off);
      s1 += __shfl_xor(s1, off);
      s2 += __shfl_xor(s2, off);
      s3 += __shfl_xor(s3, off);
      s4 += __shfl_xor(s4, off);
    }
    if (lane == 0) {
      size_t o = (size_t)bt * 8 + h;
      alpha[o] = sigm(s0 + gab[h]);
      eta[o]   = 0.1f * sigm(s1 + geb[h]);
      theta[o] = sigm(s2 + gtb[h]);
      gam[o]   = sigm(s3 + ggb[h]);
      rg[o]    = sigm(s4);
    }
  }
}

// ---------------- init M/S carries ------------------------------------------
__global__ __launch_bounds__(256) void init_carry(const float* __restrict__ w1,
    float* __restrict__ Mc, float* __restrict__ Sc) {
  int idx = blockIdx.x * 256 + threadIdx.x;   // < 65536
  Mc[idx] = w1[idx & 32767];
  Sc[idx] = 0.0f;
}

// ---------------- bootstrap chunk_a (chunk 0): err -> omega -> S scan -------
__global__ __launch_bounds__(256) void chunk_a(
    const float* __restrict__ kb, const float* __restrict__ vb,
    const float* __restrict__ eta, const float* __restrict__ theta,
    const float* __restrict__ gam,
    const float* __restrict__ Mc, float* __restrict__ Sc,
    float* __restrict__ chS, int ci) {
  __shared__ float KT[64][65];   // KT[k][c]
  __shared__ float errl[4][68];  // err[vr][c]
  __shared__ float Ml[4][64];
  __shared__ float ge_[64], gt_[64], gg_[64];
  const int tid = threadIdx.x;
  const int bh = blockIdx.x >> 4;
  const int vs = blockIdx.x & 15;
  const int b = bh >> 3, h = bh & 7;
  const int v0 = vs * 4;
  const int t0 = ci * 64;
  const int lane = tid & 63, q4 = tid >> 6;
  for (int it = 0; it < 16; ++it) {
    int c = it * 4 + q4;
    KT[lane][c] = kb[((size_t)(b * T_ + t0 + c) * H_ + h) * 64 + lane];
  }
  if (tid < 64) {
    size_t gi = (size_t)(b * T_ + t0 + tid) * H_ + h;
    ge_[tid] = eta[gi]; gt_[tid] = theta[gi]; gg_[tid] = gam[gi];
  }
  Ml[q4][lane] = Mc[((size_t)bh * 64 + v0 + q4) * 64 + lane];
  __syncthreads();
  {
    int c = lane, vr = q4;
    float p = 0.0f;
#pragma unroll
    for (int k2 = 0; k2 < 64; ++k2) p += KT[k2][c] * Ml[vr][k2];
    float vv = vb[((size_t)(b * T_ + t0 + c) * H_ + h) * 64 + v0 + vr];
    errl[vr][c] = p - vv;
  }
  __syncthreads();
  {
    const int kk = lane, vr = q4, v = v0 + vr;
    float S = Sc[((size_t)bh * 64 + v) * 64 + kk];
    float ring[8];
    float cum = 0.0f;
    float* out = chS + ((size_t)(b << 6) * 8 + h) * 4096 + (size_t)v * 64 + kk;
    for (int c8 = 0; c8 < 8; ++c8) {
#pragma unroll
      for (int j = 0; j < 8; ++j) {
        int c = c8 * 8 + j;
        float u = 0.03125f * errl[vr][c] * KT[kk][c];
        float gu = gg_[c] * u;
        cum += gu;
        if (c8 > 0) cum -= ring[j];
        ring[j] = gu;
        float mom = -ge_[c] * cum;
        S = gt_[c] * S + mom;
        out[(size_t)c * 32768] = S;
      }
    }
    Sc[((size_t)bh * 64 + v) * 64 + kk] = S;
  }
}

// ---------------- split-precision 32x32-per-wave matmul (4 waves) -----------
// Swizzled [64][64] arrays; every fragment is one 16B-aligned ds_read_b128.
__device__ __forceinline__ void mm4(const short (*Ah)[64], const short (*Al)[64],
    const short (*Bh)[64], const short (*Bl)[64],
    int wr, int wc, int l15, int kq, int sp, f4v acc[2][2]) {
#pragma unroll
  for (int kt = 0; kt < 64; kt += 32) {
    const int ra0 = wr + l15, ra1 = wr + 16 + l15;
    const int rb0 = wc + l15, rb1 = wc + 16 + l15;
    s8v a0h = *(const s8v*)&Ah[ra0][SW(ra0, kt + kq)];
    s8v a1h = *(const s8v*)&Ah[ra1][SW(ra1, kt + kq)];
    s8v b0h = *(const s8v*)&Bh[rb0][SW(rb0, kt + kq)];
    s8v b1h = *(const s8v*)&Bh[rb1][SW(rb1, kt + kq)];
    acc[0][0] = MFMA(a0h, b0h, acc[0][0]);
    acc[0][1] = MFMA(a0h, b1h, acc[0][1]);
    acc[1][0] = MFMA(a1h, b0h, acc[1][0]);
    acc[1][1] = MFMA(a1h, b1h, acc[1][1]);
    if (sp) {
      s8v a0l = *(const s8v*)&Al[ra0][SW(ra0, kt + kq)];
      s8v a1l = *(const s8v*)&Al[ra1][SW(ra1, kt + kq)];
      s8v b0l = *(const s8v*)&Bl[rb0][SW(rb0, kt + kq)];
      s8v b1l = *(const s8v*)&Bl[rb1][SW(rb1, kt + kq)];
      acc[0][0] = MFMA(a0h, b0l, acc[0][0]);
      acc[0][1] = MFMA(a0h, b1l, acc[0][1]);
      acc[1][0] = MFMA(a1h, b0l, acc[1][0]);
      acc[1][1] = MFMA(a1h, b1l, acc[1][1]);
      acc[0][0] = MFMA(a0l, b0h, acc[0][0]);
      acc[0][1] = MFMA(a0l, b1h, acc[0][1]);
      acc[1][0] = MFMA(a1l, b0h, acc[1][0]);
      acc[1][1] = MFMA(a1l, b1h, acc[1][1]);
    }
  }
}

// ---------------- polar express v5: 4 waves, swizzled LDS, b128 reads -------
// X <- aX + X*(b*At + c*At^2), At = X^T X; At held in registers p1->p2.
__global__ __launch_bounds__(256, 3) void polar_k(float* __restrict__ cs) {
  __shared__ short Xh[64][64], Xl[64][64];     // X rows (hi/lo), swizzled
  __shared__ short XTh[64][64], XTl[64][64];   // X^T rows, swizzled
  __shared__ short Zh[64][64], Zl[64][64];     // At, then Zt (symmetric)
  __shared__ float red[4];
  const int tid = threadIdx.x;
  const int lane = tid & 63;
  const int w = tid >> 6;           // 0..3
  const int wr = (w >> 1) * 32;     // 0,32
  const int wc = (w & 1) * 32;      // 0,32
  const int l15 = lane & 15;
  const int q4 = lane >> 4;
  const int kq = q4 * 8;
  float* base = cs + (size_t)blockIdx.x * 4096;
  float xr[2][2][4];   // [m2][n2][r]: element (wr+m2*16+q4*4+r, wc+n2*16+l15)
  float ss = 0.0f;
#pragma unroll
  for (int m2 = 0; m2 < 2; ++m2)
#pragma unroll
    for (int n2 = 0; n2 < 2; ++n2)
#pragma unroll
      for (int r = 0; r < 4; ++r) {
        float v = base[(wr + m2 * 16 + q4 * 4 + r) * 64 + wc + n2 * 16 + l15];
        xr[m2][n2][r] = v;
        ss += v * v;
      }
#pragma unroll
  for (int off = 32; off >= 1; off >>= 1) ss += __shfl_xor(ss, off);
  if (lane == 0) red[w] = ss;
  __syncthreads();
  float scale = 1.0f / (sqrtf(red[0] + red[1] + red[2] + red[3]) * 1.01f + 1e-7f);
#pragma unroll
  for (int m2 = 0; m2 < 2; ++m2)
#pragma unroll
    for (int n2 = 0; n2 < 2; ++n2) {
      const int rr0 = wr + m2 * 16 + q4 * 4;
      const int cc = wc + n2 * 16 + l15;
      s4v hv, lv;
#pragma unroll
      for (int r = 0; r < 4; ++r) {
        float xv = xr[m2][n2][r] * scale;
        xr[m2][n2][r] = xv;
        short hh = f2bf(xv);
        short ll = f2bf(xv - bf2f(hh));
        hv[r] = hh; lv[r] = ll;
        Xh[rr0 + r][SW(rr0 + r, cc)] = hh;
        Xl[rr0 + r][SW(rr0 + r, cc)] = ll;
      }
      *(s4v*)&XTh[cc][SW(cc, rr0)] = hv;
      *(s4v*)&XTl[cc][SW(cc, rr0)] = lv;
    }
  __syncthreads();

  for (int it = 0; it < 5; ++it) {
    const int sp = (it < 4);
    // ---- p1: At = X^T X = mm(XT,XT); At stays in regs; store sym into Z ---
    f4v at[2][2];
#pragma unroll
    for (int m2 = 0; m2 < 2; ++m2)
#pragma unroll
      for (int n2 = 0; n2 < 2; ++n2)
#pragma unroll
        for (int r = 0; r < 4; ++r) at[m2][n2][r] = 0.0f;
    mm4(XTh, XTl, XTh, XTl, wr, wc, l15, kq, sp, at);
#pragma unroll
    for (int m2 = 0; m2 < 2; ++m2)
#pragma unroll
      for (int n2 = 0; n2 < 2; ++n2) {
        const int rr0 = wr + m2 * 16 + q4 * 4;
        const int cc = wc + n2 * 16 + l15;
        s4v hv, lv;
#pragma unroll
        for (int r = 0; r < 4; ++r) {
          float a = at[m2][n2][r];
          short hh = f2bf(a);
          hv[r] = hh; lv[r] = f2bf(a - bf2f(hh));
        }
        *(s4v*)&Zh[cc][SW(cc, rr0)] = hv;
        if (sp) *(s4v*)&Zl[cc][SW(cc, rr0)] = lv;
      }
    __syncthreads();                       // publish At
    // ---- p2: A2 = mm(Z,Z); Zt = b*At + c*A2 (At from registers) ----
    f4v a2[2][2];
#pragma unroll
    for (int m2 = 0; m2 < 2; ++m2)
#pragma unroll
      for (int n2 = 0; n2 < 2; ++n2)
#pragma unroll
        for (int r = 0; r < 4; ++r) a2[m2][n2][r] = 0.0f;
    mm4(Zh, Zl, Zh, Zl, wr, wc, l15, kq, sp, a2);
    float zt[2][2][4];
#pragma unroll
    for (int m2 = 0; m2 < 2; ++m2)
#pragma unroll
      for (int n2 = 0; n2 < 2; ++n2)
#pragma unroll
        for (int r = 0; r < 4; ++r)
          zt[m2][n2][r] = -4.7750f * at[m2][n2][r] + 2.0315f * a2[m2][n2][r];
    __syncthreads();                       // all Z reads complete
#pragma unroll
    for (int m2 = 0; m2 < 2; ++m2)
#pragma unroll
      for (int n2 = 0; n2 < 2; ++n2) {
        const int rr0 = wr + m2 * 16 + q4 * 4;
        const int cc = wc + n2 * 16 + l15;
        s4v hv, lv;
#pragma unroll
        for (int r = 0; r < 4; ++r) {
          float zv = zt[m2][n2][r];
          short hh = f2bf(zv);
          hv[r] = hh; lv[r] = f2bf(zv - bf2f(hh));
        }
        *(s4v*)&Zh[cc][SW(cc, rr0)] = hv;
        if (sp) *(s4v*)&Zl[cc][SW(cc, rr0)] = lv;
      }
    __syncthreads();                       // publish Zt
    // ---- p3: X_new = a*X + mm(X, Zt) ----
    f4v q3[2][2];
#pragma unroll
    for (int m2 = 0; m2 < 2; ++m2)
#pragma unroll
      for (int n2 = 0; n2 < 2; ++n2)
#pragma unroll
        for (int r = 0; r < 4; ++r) q3[m2][n2][r] = 0.0f;
    mm4(Xh, Xl, Zh, Zl, wr, wc, l15, kq, sp, q3);
#pragma unroll
    for (int m2 = 0; m2 < 2; ++m2)
#pragma unroll
      for (int n2 = 0; n2 < 2; ++n2)
#pragma unroll
        for (int r = 0; r < 4; ++r)
          xr[m2][n2][r] = 3.4445f * xr[m2][n2][r] + q3[m2][n2][r];
    if (it < 4) {
      __syncthreads();                     // all X reads complete
      const int slo = (it < 3);            // next iter reads lo only if split
#pragma unroll
      for (int m2 = 0; m2 < 2; ++m2)
#pragma unroll
        for (int n2 = 0; n2 < 2; ++n2) {
          const int rr0 = wr + m2 * 16 + q4 * 4;
          const int cc = wc + n2 * 16 + l15;
          s4v hv, lv;
#pragma unroll
          for (int r = 0; r < 4; ++r) {
            float xv = xr[m2][n2][r];
            short hh = f2bf(xv);
            short ll = f2bf(xv - bf2f(hh));
            hv[r] = hh; lv[r] = ll;
            Xh[rr0 + r][SW(rr0 + r, cc)] = hh;
            if (slo) Xl[rr0 + r][SW(rr0 + r, cc)] = ll;
          }
          *(s4v*)&XTh[cc][SW(cc, rr0)] = hv;
          if (slo) *(s4v*)&XTl[cc][SW(cc, rr0)] = lv;
        }
      __syncthreads();
    }
  }
  // write back fp32 (in place)
#pragma unroll
  for (int m2 = 0; m2 < 2; ++m2)
#pragma unroll
    for (int n2 = 0; n2 < 2; ++n2)
#pragma unroll
      for (int r = 0; r < 4; ++r)
        base[(wr + m2 * 16 + q4 * 4 + r) * 64 + wc + n2 * 16 + l15] = xr[m2][n2][r];
}

// ---------------- fused: chunk_c(ci) + chunk_a(ci+1) ------------------------
// Phase A: scan with DEFERRED reductions — pure 64-FMA chain, then 64
// independent reduce trees at full ILP, then lane-0 stores. Two 32-halves
// keep VGPR ~100.
__global__ __launch_bounds__(256, 1) void chunk_ca(
    const float* __restrict__ qb, const float* __restrict__ kb,
    const float* __restrict__ vb,
    const float* __restrict__ alpha, const float* __restrict__ eta,
    const float* __restrict__ theta, const float* __restrict__ gam,
    float* __restrict__ Mc, float* __restrict__ Sc,
    float* __restrict__ chS, float* __restrict__ yb, int ci) {
  __shared__ float KT[64][65];
  __shared__ float errl[4][68];
  __shared__ float Ml[4][64];
  __shared__ float ge_[64], gt_[64], gg_[64];
  const int tid = threadIdx.x, lane = tid & 63, w = tid >> 6;
  const int bh = blockIdx.x >> 4, vs = blockIdx.x & 15;
  const int b = bh >> 3, h = bh & 7;
  const int v0 = vs * 4, v = v0 + w;
  const int t0 = ci * 64;
  float M = Mc[((size_t)bh * 64 + v) * 64 + lane];
  // ---- phase A ----
  const float* op = chS + ((size_t)(b << 6) * 8 + h) * 4096 + (size_t)v * 64 + lane;
  const float* qp = qb + ((size_t)(b * T_ + t0) * 8 + h) * 64 + lane;
  float* yp = yb + ((size_t)(b * T_ + t0) * 8 + h) * 64 + v;
  float av = alpha[(size_t)(b * T_ + t0 + lane) * 8 + h];
#pragma unroll
  for (int half = 0; half < 2; ++half) {
    const int cb = half * 32;
    float ov[32], qv[32], p[32];
#pragma unroll
    for (int j = 0; j < 32; ++j) ov[j] = op[(size_t)(cb + j) * 32768];
#pragma unroll
    for (int j = 0; j < 32; ++j) qv[j] = qp[(size_t)(cb + j) * 512];
#pragma unroll
    for (int j = 0; j < 32; ++j) {
      M = __builtin_fmaf(__shfl(av, cb + j), M, ov[j]);
      p[j] = M * qv[j];
    }
#pragma unroll
    for (int j = 0; j < 32; ++j) {
#pragma unroll
      for (int off = 32; off >= 1; off >>= 1) p[j] += __shfl_xor(p[j], off);
    }
    if (lane == 0) {
#pragma unroll
      for (int j = 0; j < 32; ++j) yp[(size_t)(cb + j) * 512] = p[j];
    }
  }
  Mc[((size_t)bh * 64 + v) * 64 + lane] = M;
  if (ci == 15) return;
  // ---- phase B: err + omega + S-scan for chunk ci+1 ----
  const int t1 = t0 + 64;
  Ml[w][lane] = M;
  for (int it = 0; it < 16; ++it) {
    int c = it * 4 + w;
    KT[lane][c] = kb[((size_t)(b * T_ + t1 + c) * 8 + h) * 64 + lane];
  }
  if (tid < 64) {
    size_t gi = (size_t)(b * T_ + t1 + tid) * 8 + h;
    ge_[tid] = eta[gi]; gt_[tid] = theta[gi]; gg_[tid] = gam[gi];
  }
  __syncthreads();
  {
    int c = lane, vr = w;
    float s0 = 0, s1 = 0, s2 = 0, s3 = 0;
#pragma unroll
    for (int k2 = 0; k2 < 64; k2 += 4) {
      s0 += KT[k2 + 0][c] * Ml[vr][k2 + 0];
      s1 += KT[k2 + 1][c] * Ml[vr][k2 + 1];
      s2 += KT[k2 + 2][c] * Ml[vr][k2 + 2];
      s3 += KT[k2 + 3][c] * Ml[vr][k2 + 3];
    }
    float vv = vb[((size_t)(b * T_ + t1 + c) * 8 + h) * 64 + v0 + vr];
    errl[vr][c] = (s0 + s1) + (s2 + s3) - vv;
  }
  __syncthreads();
  {
    const int kk = lane, vr = w, vv2 = v0 + vr;
    float S = Sc[((size_t)bh * 64 + vv2) * 64 + kk];
    float ring[8];
    float cum = 0.0f;
    float* out = chS + ((size_t)(b << 6) * 8 + h) * 4096 + (size_t)vv2 * 64 + kk;
    for (int c8 = 0; c8 < 8; ++c8) {
#pragma unroll
      for (int j = 0; j < 8; ++j) {
        int c = c8 * 8 + j;
        float u = 0.03125f * errl[vr][c] * KT[kk][c];
        float gu = gg_[c] * u;
        cum += gu;
        if (c8 > 0) cum -= ring[j];
        ring[j] = gu;
        float mom = -ge_[c] * cum;
        S = gt_[c] * S + mom;
        out[(size_t)c * 32768] = S;
      }
    }
    Sc[((size_t)bh * 64 + vv2) * 64 + kk] = S;
  }
}

// ---------------- RMS-norm * (1+ln_gamma) * rg ------------------------------
__global__ __launch_bounds__(256) void norm_k(const float* __restrict__ yb,
    const float* __restrict__ lng, const float* __restrict__ rg,
    float* __restrict__ yn) {
  const int lane = threadIdx.x & 63;
  const int gw = blockIdx.x * 4 + (threadIdx.x >> 6);  // (b*T+t)*8 + h
  const int h = gw & 7;
  const int bt = gw >> 3;
  float y = yb[(size_t)gw * 64 + lane];
  float s = y * y;
#pragma unroll
  for (int off = 32; off >= 1; off >>= 1) s += __shfl_xor(s, off);
  float r = rsqrtf(s * (1.0f / 64.0f) + 1e-6f);
  yn[(size_t)gw * 64 + lane] = y * r * (1.0f + lng[h * 64 + lane]) * rg[(size_t)bt * 8 + h];
}

// ---------------- launcher --------------------------------------------------
extern "C" void kernel_launch(void* const* d_in, const int* in_sizes, int n_in,
                              void* d_out, int out_size, void* d_ws, size_t ws_size,
                              hipStream_t stream) {
  (void)in_sizes; (void)n_in; (void)out_size; (void)ws_size;
  const float* x   = (const float*)d_in[0];
  const float* Wq  = (const float*)d_in[1];
  const float* Wk  = (const float*)d_in[2];
  const float* Wv  = (const float*)d_in[3];
  const float* Wpr = (const float*)d_in[4];
  const float* cqw = (const float*)d_in[5];
  const float* cqb = (const float*)d_in[6];
  const float* ckw = (const float*)d_in[7];
  const float* ckb = (const float*)d_in[8];
  const float* cvw = (const float*)d_in[9];
  const float* cvb = (const float*)d_in[10];
  const float* gaw = (const float*)d_in[11];
  const float* gab = (const float*)d_in[12];
  const float* gew = (const float*)d_in[13];
  const float* geb = (const float*)d_in[14];
  const float* gtw = (const float*)d_in[15];
  const float* gtb = (const float*)d_in[16];
  const float* ggw = (const float*)d_in[17];
  const float* ggb = (const float*)d_in[18];
  const float* pc  = (const float*)d_in[19];
  const float* lng = (const float*)d_in[20];
  const float* w1  = (const float*)d_in[21];
  const float* rgw = (const float*)d_in[22];
  float* outp = (float*)d_out;

  float* chS = (float*)d_ws;      // 16 MB (4M floats); xq/xk/xv/yn alias it
  float* xq = chS;
  float* xk = chS + 1048576;
  float* xv = chS + 2 * 1048576;
  float* yn = chS;
  char* wp = (char*)d_ws + (size_t)16 * 1024 * 1024;
  auto alloc = [&](size_t bytes) {
    char* p = wp;
    wp += (bytes + 255) & ~(size_t)255;
    return p;
  };
  const size_t BT = (size_t)B_ * T_;  // 2048
  float* qb = (float*)alloc(BT * 512 * 4);
  float* kb = (float*)alloc(BT * 512 * 4);
  float* vb = (float*)alloc(BT * 512 * 4);
  float* yb = (float*)alloc(BT * 512 * 4);
  float* alpha = (float*)alloc(BT * 8 * 4);
  float* eta   = (float*)alloc(BT * 8 * 4);
  float* theta = (float*)alloc(BT * 8 * 4);
  float* gam   = (float*)alloc(BT * 8 * 4);
  float* rg    = (float*)alloc(BT * 8 * 4);
  float* Mc = (float*)alloc((size_t)65536 * 4);
  float* Sc = (float*)alloc((size_t)65536 * 4);

  init_carry<<<dim3(256), dim3(256), 0, stream>>>(w1, Mc, Sc);
  gemm_qkv<<<dim3(32, 24), dim3(256), 0, stream>>>(x, Wq, Wk, Wv, xq, xk, xv);
  conv3_k<<<dim3(12288), dim3(256), 0, stream>>>(xq, xk, xv, cqw, cqb, ckw, ckb,
                                                 cvw, cvb, pc, qb, kb, vb);
  gates_k<<<dim3(512), dim3(256), 0, stream>>>(x, gaw, gab, gew, geb, gtw, gtb,
                                               ggw, ggb, rgw, alpha, eta, theta, gam, rg);
  chunk_a<<<dim3(256), dim3(256), 0, stream>>>(kb, vb, eta, theta, gam, Mc, Sc, chS, 0);
  for (int ci = 0; ci < 16; ++ci) {
    polar_k<<<dim3(1024), dim3(256), 0, stream>>>(chS);
    chunk_ca<<<dim3(256), dim3(256), 0, stream>>>(qb, kb, vb, alpha, eta, theta, gam,
                                                  Mc, Sc, chS, yb, ci);
  }
  norm_k<<<dim3(4096), dim3(256), 0, stream>>>(yb, lng, rg, yn);
  gemm_bt<<<dim3(32, 8), dim3(256), 0, stream>>>(yn, Wpr, outp, 2048, 512, 512);
}